// Round 14
// baseline (191.291 us; speedup 1.0000x reference)
//
#include <hip/hip_runtime.h>
#include <math.h>

#define NEG_INF (-1e9f)
#define EPS 1e-5f

typedef __attribute__((ext_vector_type(8))) short short8;
typedef __attribute__((ext_vector_type(4))) float floatx4;

__device__ __forceinline__ unsigned short f2bf(float x) {
    union { float f; unsigned u; } v; v.f = x;
    unsigned r = v.u + 0x7fffu + ((v.u >> 16) & 1u);
    return (unsigned short)(r >> 16);
}

// async global->LDS, 16B per lane: LDS dest = wave-uniform base (+lane*16 by HW),
// global src per-lane (enables source pre-swizzle for swizzled LDS layouts).
__device__ __forceinline__ void gl2lds16(const void* g, void* l) {
    __builtin_amdgcn_global_load_lds(
        (const __attribute__((address_space(1))) unsigned int*)g,
        (__attribute__((address_space(3))) unsigned int*)l, 16, 0, 0);
}

// ---------------- weight transposes + mask-storage detect + node-mask pack ----------------
__global__ void transpose_prep_kernel(const float* __restrict__ w_qkv, const float* __restrict__ w_out,
                                      const float* __restrict__ w_ff1, const float* __restrict__ w_ff2,
                                      float* __restrict__ wqkvT, float* __restrict__ woutT,
                                      float* __restrict__ wff1T, float* __restrict__ wff2T,
                                      const unsigned int* __restrict__ sm, int* __restrict__ flag,
                                      const float* __restrict__ nm, unsigned int* __restrict__ nmb) {
    if (blockIdx.x < 512) {
        int idx = blockIdx.x * 256 + threadIdx.x;        // 131072 total
        if (idx < 49152) {
            int r = idx / 128, c = idx % 128;
            wqkvT[c * 384 + r] = w_qkv[idx];
        } else if (idx < 65536) {
            int i = idx - 49152; int r = i / 128, c = i % 128;
            woutT[c * 128 + r] = w_out[i];
        } else if (idx < 98304) {
            int i = idx - 65536; int r = i / 128, c = i % 128;
            wff1T[c * 256 + r] = w_ff1[i];
        } else {
            int i = idx - 98304; int r = i / 256, c = i % 256;
            wff2T[c * 128 + r] = w_ff2[i];
        }
    } else if (blockIdx.x == 512) {
        __shared__ int bad;
        if (threadIdx.x == 0) bad = 0;
        __syncthreads();
        for (int i = threadIdx.x; i < 4096; i += 256) {
            if (sm[i] > 1u) bad = 1;   // impossible for int32 bool storage
        }
        __syncthreads();
        if (threadIdx.x == 0) *flag = bad;   // 1 -> byte storage, 0 -> int32
    } else {
        const int t = threadIdx.x;            // 256 = 4 b * 64 words
        const int b = t >> 6, w32 = t & 63;
        unsigned u = 0;
#pragma unroll
        for (int j = 0; j < 32; ++j)
            u |= (nm[b * 2048 + w32 * 32 + j] > 0.f ? 1u : 0u) << j;
        nmb[t] = u;
    }
}

// ---------------- combined key-mask bits: cbits[(b*2048+q)*64 + k/32] ----------------
__global__ void mask_prep_kernel(const unsigned char* __restrict__ smraw,
                                 const int* __restrict__ flag,
                                 const unsigned int* __restrict__ nmb,
                                 unsigned int* __restrict__ cbits) {
    const int idx = blockIdx.x * 256 + threadIdx.x;   // 524288 total
    const int b = idx >> 17;
    const int q = (idx >> 6) & 2047;
    const int w32 = idx & 63;
    unsigned u = 0;
    if (*flag) {   // byte storage
        const uint4* p = reinterpret_cast<const uint4*>(
            smraw + (size_t)(b * 2048 + q) * 2048 + w32 * 32);
        uint4 a = p[0], c = p[1];
        unsigned wd0 = a.x, wd1 = a.y, wd2 = a.z, wd3 = a.w;
        unsigned wd4 = c.x, wd5 = c.y, wd6 = c.z, wd7 = c.w;
#define BYTES4(v, sh) \
        u |= ((v) & 0xffu ? 1u : 0u) << (sh); \
        u |= ((v) & 0xff00u ? 1u : 0u) << ((sh) + 1); \
        u |= ((v) & 0xff0000u ? 1u : 0u) << ((sh) + 2); \
        u |= ((v) & 0xff000000u ? 1u : 0u) << ((sh) + 3);
        BYTES4(wd0, 0) BYTES4(wd1, 4) BYTES4(wd2, 8) BYTES4(wd3, 12)
        BYTES4(wd4, 16) BYTES4(wd5, 20) BYTES4(wd6, 24) BYTES4(wd7, 28)
#undef BYTES4
    } else {       // int32 storage
        const uint4* p = reinterpret_cast<const uint4*>(
            reinterpret_cast<const unsigned int*>(smraw) + (size_t)(b * 2048 + q) * 2048 + w32 * 32);
#pragma unroll
        for (int wi = 0; wi < 8; ++wi) {
            uint4 a = p[wi];
            u |= (a.x ? 1u : 0u) << (wi * 4);
            u |= (a.y ? 1u : 0u) << (wi * 4 + 1);
            u |= (a.z ? 1u : 0u) << (wi * 4 + 2);
            u |= (a.w ? 1u : 0u) << (wi * 4 + 3);
        }
    }
    cbits[idx] = u & nmb[b * 64 + w32];
}

// ---------------- QKV projection -> bf16 Q,K [bh][l][32]; bf16 V^T [bh][d][k] ----------------
// grid: B*L/16 = 512 blocks, block: 384 threads (one per output column)
__global__ void qkv_kernel(const float* __restrict__ h, const float* __restrict__ wT,
                           const float* __restrict__ bqkv,
                           unsigned short* __restrict__ qb, unsigned short* __restrict__ kbm,
                           unsigned short* __restrict__ vtb) {
    __shared__ __align__(16) float hs[16 * 128];
    const int tid = threadIdx.x;
    const int row0 = blockIdx.x * 16;
    for (int i = tid; i < 2048; i += 384) hs[i] = h[row0 * 128 + i];
    __syncthreads();

    const int c = tid;
    float acc[16];
#pragma unroll
    for (int r = 0; r < 16; ++r) acc[r] = 0.f;

    for (int d0 = 0; d0 < 128; d0 += 4) {
        float w0 = wT[(d0 + 0) * 384 + c];
        float w1 = wT[(d0 + 1) * 384 + c];
        float w2 = wT[(d0 + 2) * 384 + c];
        float w3 = wT[(d0 + 3) * 384 + c];
#pragma unroll
        for (int r = 0; r < 16; ++r) {
            float4 h4 = *reinterpret_cast<const float4*>(&hs[r * 128 + d0]);
            acc[r] = fmaf(w0, h4.x, acc[r]);
            acc[r] = fmaf(w1, h4.y, acc[r]);
            acc[r] = fmaf(w2, h4.z, acc[r]);
            acc[r] = fmaf(w3, h4.w, acc[r]);
        }
    }
    const int part = c >> 7;        // 0=q 1=k 2=v
    const int cc = c & 127;
    const int head = cc >> 5;
    const int dd = cc & 31;
    const float bias = bqkv[c];
    const float scale = (part == 0) ? 0.17677669529663687f : 1.0f; // 1/sqrt(32) into q
#pragma unroll
    for (int r = 0; r < 16; ++r) {
        int grow = row0 + r;
        int b = grow >> 11, l = grow & 2047;
        int bh = b * 4 + head;
        unsigned short val = f2bf((acc[r] + bias) * scale);
        if (part == 0)      qb[((size_t)bh * 2048 + l) * 32 + dd] = val;
        else if (part == 1) kbm[((size_t)bh * 2048 + l) * 32 + dd] = val;
        else                vtb[((size_t)bh * 32 + dd) * 2048 + l] = val;
    }
}

// ---------------- attention: bf16 MFMA, independent waves, per-wave bias staging ------
// grid: 2048 blocks, block: 128 threads = 2 INDEPENDENT waves (khalf 0/1, split-K).
// NO barriers in the main loop: each wave owns 16 q-rows x 1024 k, stages its own
// 4KB bias tile 2 ahead via gl2lds into a wave-private double buffer; K/V fragments
// loaded directly from L2 (XCD swizzle keeps each bh's K/V on one XCD).
// Landing guarantee: compiler's vmcnt wait for tile-t K frags force-retires (in-order)
// the bias(t) DMA issued 2 tiles earlier. Split-K merge at the end (2 barriers).
__global__ __launch_bounds__(128, 4) void attn_kernel(
        const unsigned short* __restrict__ qb, const unsigned short* __restrict__ kbm,
        const unsigned short* __restrict__ vtb, const float* __restrict__ bias,
        const unsigned int* __restrict__ cbits, const float* __restrict__ nmask,
        float* __restrict__ aout) {
    __shared__ __align__(16) float bias_lds[2][2][1024];          // 16 KB: [wave][slot][16x64]
    __shared__ __align__(16) unsigned short p_lds[2][16 * 72];    // 4.5 KB, wave-private

    const int tid = threadIdx.x;
    const int w = tid >> 6;            // khalf
    const int L = tid & 63;
    const int lb = (blockIdx.x & 7) * 256 + (blockIdx.x >> 3);   // bijective, 2048%8==0
    const int bh = lb >> 7, qt = lb & 127;
    const int b = bh >> 2, hh = bh & 3;
    const int q0b = qt * 16;
    const int q = L & 15, g = L >> 4;

    const unsigned short* kbase = kbm + (size_t)bh * 2048 * 32 + g * 8;
    const unsigned short* vbase = vtb + (size_t)bh * 32 * 2048 + g * 8;
    const float* bias_wb = bias + ((size_t)bh * 2048 + q0b) * 2048 + w * 1024;
    const short8 qf = *reinterpret_cast<const short8*>(
        qb + ((size_t)bh * 2048 + q0b + q) * 32 + g * 8);
    const unsigned int* crow = cbits + (size_t)(b * 2048 + q0b + q) * 64 + w * 32;

    // staging map: call i, lane L -> LDS row i*4+(L>>4), chunk L&15;
    // source chunk pre-swizzled: c = (L&15) ^ (row&7)
    auto stage = [&](int slot, int t) {
        const int k0 = t * 64;
#pragma unroll
        for (int i = 0; i < 4; ++i) {
            const int row = i * 4 + (L >> 4);
            const int c = (L & 15) ^ (row & 7);
            gl2lds16(bias_wb + (size_t)row * 2048 + k0 + c * 4,
                     (char*)&bias_lds[w][slot][0] + i * 1024);
        }
    };

    stage(0, 0);
    stage(1, 1);
    asm volatile("s_waitcnt vmcnt(4)" ::: "memory");   // bias(0) landed; bias(1) in flight

    float mrun = -3.0e38f, lrun = 0.f;
    floatx4 o0 = {0.f, 0.f, 0.f, 0.f}, o1 = {0.f, 0.f, 0.f, 0.f};
    const floatx4 zacc = {0.f, 0.f, 0.f, 0.f};
    unsigned short* pl = &p_lds[w][q * 72];

    // bias read offsets: lane (q,g), m: byte = q*256 + (((4m+g)^(q&7))<<4)
    int boff[4];
#pragma unroll
    for (int mm = 0; mm < 4; ++mm)
        boff[mm] = q * 256 + ((((mm << 2) + g) ^ (q & 7)) << 4);

    for (int t = 0; t < 16; ++t) {
        const int k0 = w * 1024 + t * 64;
        // ---- K fragments (L2, coalesced 1KB/instr) ----
        short8 kf0 = *reinterpret_cast<const short8*>(kbase + (size_t)(k0 +  0 + q) * 32);
        short8 kf1 = *reinterpret_cast<const short8*>(kbase + (size_t)(k0 + 16 + q) * 32);
        short8 kf2 = *reinterpret_cast<const short8*>(kbase + (size_t)(k0 + 32 + q) * 32);
        short8 kf3 = *reinterpret_cast<const short8*>(kbase + (size_t)(k0 + 48 + q) * 32);
        // ---- V^T fragments (L2) ----
        short8 vf00 = *reinterpret_cast<const short8*>(vbase + (size_t)(q     ) * 2048 + k0);
        short8 vf01 = *reinterpret_cast<const short8*>(vbase + (size_t)(q     ) * 2048 + k0 + 32);
        short8 vf10 = *reinterpret_cast<const short8*>(vbase + (size_t)(16 + q) * 2048 + k0);
        short8 vf11 = *reinterpret_cast<const short8*>(vbase + (size_t)(16 + q) * 2048 + k0 + 32);
        uint2 cw = *reinterpret_cast<const uint2*>(crow + t * 2);

        // ---- QK^T ----
        float s[16];
        {
            floatx4 r0 = __builtin_amdgcn_mfma_f32_16x16x32_bf16(kf0, qf, zacc, 0, 0, 0);
            floatx4 r1 = __builtin_amdgcn_mfma_f32_16x16x32_bf16(kf1, qf, zacc, 0, 0, 0);
            floatx4 r2 = __builtin_amdgcn_mfma_f32_16x16x32_bf16(kf2, qf, zacc, 0, 0, 0);
            floatx4 r3 = __builtin_amdgcn_mfma_f32_16x16x32_bf16(kf3, qf, zacc, 0, 0, 0);
            s[0] = r0[0]; s[1] = r0[1]; s[2] = r0[2]; s[3] = r0[3];
            s[4] = r1[0]; s[5] = r1[1]; s[6] = r1[2]; s[7] = r1[3];
            s[8] = r2[0]; s[9] = r2[1]; s[10] = r2[2]; s[11] = r2[3];
            s[12] = r3[0]; s[13] = r3[1]; s[14] = r3[2]; s[15] = r3[3];
        }
        // ---- bias fragments from wave-private LDS (staged 2 tiles ago) ----
        const char* bl = (const char*)&bias_lds[w][t & 1][0];
        float4 bq0 = *reinterpret_cast<const float4*>(bl + boff[0]);
        float4 bq1 = *reinterpret_cast<const float4*>(bl + boff[1]);
        float4 bq2 = *reinterpret_cast<const float4*>(bl + boff[2]);
        float4 bq3 = *reinterpret_cast<const float4*>(bl + boff[3]);
        float bvv[16];
        bvv[0] = bq0.x; bvv[1] = bq0.y; bvv[2] = bq0.z; bvv[3] = bq0.w;
        bvv[4] = bq1.x; bvv[5] = bq1.y; bvv[6] = bq1.z; bvv[7] = bq1.w;
        bvv[8] = bq2.x; bvv[9] = bq2.y; bvv[10] = bq2.z; bvv[11] = bq2.w;
        bvv[12] = bq3.x; bvv[13] = bq3.y; bvv[14] = bq3.z; bvv[15] = bq3.w;
#pragma unroll
        for (int i = 0; i < 16; ++i) {
            const int mm = i >> 2, reg = i & 3;
            const unsigned word = (mm < 2) ? cw.x : cw.y;
            const int sh = 16 * (mm & 1) + 4 * g + reg;
            const bool keep = (word >> sh) & 1;
            s[i] = keep ? (s[i] + bvv[i]) : NEG_INF;
        }
        // ---- online softmax (in-lane 16 + 2 shfl) ----
        float tm = s[0];
#pragma unroll
        for (int i = 1; i < 16; ++i) tm = fmaxf(tm, s[i]);
        tm = fmaxf(tm, __shfl_xor(tm, 16));
        tm = fmaxf(tm, __shfl_xor(tm, 32));
        const float mn = fmaxf(mrun, tm);
        const float f = __expf(mrun - mn);
        mrun = mn;
        float p[16], ts = 0.f;
#pragma unroll
        for (int i = 0; i < 16; ++i) { p[i] = __expf(s[i] - mn); ts += p[i]; }
        ts += __shfl_xor(ts, 16);
        ts += __shfl_xor(ts, 32);
        lrun = lrun * f + ts;
        o0 *= f; o1 *= f;
        // ---- pack P -> bf16, stage in wave-private LDS row (stride 72) ----
#pragma unroll
        for (int mm = 0; mm < 4; ++mm) {
            unsigned u0 = (unsigned)f2bf(p[4 * mm]) | ((unsigned)f2bf(p[4 * mm + 1]) << 16);
            unsigned u1 = (unsigned)f2bf(p[4 * mm + 2]) | ((unsigned)f2bf(p[4 * mm + 3]) << 16);
            *reinterpret_cast<unsigned int*>(pl + 16 * mm + 4 * g) = u0;
            *reinterpret_cast<unsigned int*>(pl + 16 * mm + 4 * g + 2) = u1;
        }
        // ---- PV: B-frag = own row's 8 consecutive k ----
        short8 pb0 = *reinterpret_cast<const short8*>(pl + g * 8);
        short8 pb1 = *reinterpret_cast<const short8*>(pl + 32 + g * 8);
        o0 = __builtin_amdgcn_mfma_f32_16x16x32_bf16(vf00, pb0, o0, 0, 0, 0);
        o0 = __builtin_amdgcn_mfma_f32_16x16x32_bf16(vf01, pb1, o0, 0, 0, 0);
        o1 = __builtin_amdgcn_mfma_f32_16x16x32_bf16(vf10, pb0, o1, 0, 0, 0);
        o1 = __builtin_amdgcn_mfma_f32_16x16x32_bf16(vf11, pb1, o1, 0, 0, 0);

        // ---- per-wave pipeline advance: stage bias(t+2) into freed slot ----
        if (t < 14) stage(t & 1, t + 2);
    }

    // ---- split-K merge via wave-1's own bias buffer (it no longer reads it) ----
    float* mb = &bias_lds[1][0][0];    // 640 floats needed, 4096 available
    if (w == 1) {
        float* dst = mb + L * 10;
        dst[0] = mrun; dst[1] = lrun;
        dst[2] = o0[0]; dst[3] = o0[1]; dst[4] = o0[2]; dst[5] = o0[3];
        dst[6] = o1[0]; dst[7] = o1[1]; dst[8] = o1[2]; dst[9] = o1[3];
    }
    __syncthreads();
    if (w == 0) {
        const float* src = mb + L * 10;
        const float m2 = src[0], l2 = src[1];
        const float mm = fmaxf(mrun, m2);
        const float f1 = __expf(mrun - mm), f2 = __expf(m2 - mm);
        const float l = lrun * f1 + l2 * f2;
        const int qrow = q0b + q;
        const float nmq = nmask[b * 2048 + qrow];
        const float inv = (nmq > 0.f) ? (1.f / l) : 0.f;
        const float a1 = f1 * inv, a2 = f2 * inv;
        float* op = aout + ((size_t)b * 2048 + qrow) * 128 + hh * 32 + g * 4;
        *reinterpret_cast<float4*>(op) = make_float4(
            o0[0] * a1 + src[2] * a2, o0[1] * a1 + src[3] * a2,
            o0[2] * a1 + src[4] * a2, o0[3] * a1 + src[5] * a2);
        *reinterpret_cast<float4*>(op + 16) = make_float4(
            o1[0] * a1 + src[6] * a2, o1[1] * a1 + src[7] * a2,
            o1[2] * a1 + src[8] * a2, o1[3] * a1 + src[9] * a2);
    }
}

// ---------------- LN stats helper (16 rows x 128 cols in LDS) ----------------
__device__ __forceinline__ void ln_stats(const float* buf, float* mu_s, float* rs_s, int tid) {
    int row = tid >> 4, sl = tid & 15;
    float4 x0 = *reinterpret_cast<const float4*>(&buf[row * 128 + sl * 8]);
    float4 x1 = *reinterpret_cast<const float4*>(&buf[row * 128 + sl * 8 + 4]);
    float sum = x0.x + x0.y + x0.z + x0.w + x1.x + x1.y + x1.z + x1.w;
    float sq = x0.x * x0.x + x0.y * x0.y + x0.z * x0.z + x0.w * x0.w +
               x1.x * x1.x + x1.y * x1.y + x1.z * x1.z + x1.w * x1.w;
#pragma unroll
    for (int off = 8; off > 0; off >>= 1) {
        sum += __shfl_xor(sum, off);
        sq += __shfl_xor(sq, off);
    }
    if (sl == 0) {
        float mu = sum * (1.f / 128.f);
        float var = sq * (1.f / 128.f) - mu * mu;
        mu_s[row] = mu;
        rs_s[row] = rsqrtf(var + EPS);
    }
}

// ---------------- fused epilogue: out-proj + res + LN1 + FFN + res + LN2 + mask ----------------
// grid: B*L/16 = 512 blocks, block: 256 threads
__global__ void epilogue_kernel(const float* __restrict__ aout, const float* __restrict__ h,
                                const float* __restrict__ woutT, const float* __restrict__ bout,
                                const float* __restrict__ wff1T, const float* __restrict__ bff1,
                                const float* __restrict__ wff2T, const float* __restrict__ bff2,
                                const float* __restrict__ g1, const float* __restrict__ b1,
                                const float* __restrict__ g2, const float* __restrict__ b2,
                                const float* __restrict__ nmask, float* __restrict__ out) {
    __shared__ __align__(16) float A[16 * 128];
    __shared__ __align__(16) float Hb[16 * 128];
    __shared__ __align__(16) float F[16 * 256];
    __shared__ float mu_s[16], rs_s[16];

    const int tid = threadIdx.x;
    const int row0 = blockIdx.x * 16;
    for (int i = tid; i < 2048; i += 256) {
        A[i] = aout[row0 * 128 + i];
        Hb[i] = h[row0 * 128 + i];
    }
    __syncthreads();

    const int g = tid >> 7, c = tid & 127;

    // --- out-projection ---
    float acc[8];
#pragma unroll
    for (int r = 0; r < 8; ++r) acc[r] = 0.f;
    for (int d0 = 0; d0 < 128; d0 += 4) {
        float w0 = woutT[(d0 + 0) * 128 + c];
        float w1 = woutT[(d0 + 1) * 128 + c];
        float w2 = woutT[(d0 + 2) * 128 + c];
        float w3 = woutT[(d0 + 3) * 128 + c];
#pragma unroll
        for (int r = 0; r < 8; ++r) {
            float4 a4 = *reinterpret_cast<const float4*>(&A[(g * 8 + r) * 128 + d0]);
            acc[r] = fmaf(w0, a4.x, acc[r]);
            acc[r] = fmaf(w1, a4.y, acc[r]);
            acc[r] = fmaf(w2, a4.z, acc[r]);
            acc[r] = fmaf(w3, a4.w, acc[r]);
        }
    }
    float bo = bout[c];
#pragma unroll
    for (int r = 0; r < 8; ++r) {
        int row = g * 8 + r;
        Hb[row * 128 + c] += acc[r] + bo;   // h + attn_out
    }
    __syncthreads();

    ln_stats(Hb, mu_s, rs_s, tid);
    __syncthreads();
    float g1c = g1[c], b1c = b1[c];
#pragma unroll
    for (int r = 0; r < 8; ++r) {
        int row = g * 8 + r;
        float v = (Hb[row * 128 + c] - mu_s[row]) * rs_s[row] * g1c + b1c;
        Hb[row * 128 + c] = v;              // h1
    }
    __syncthreads();

    // --- FF1 + ReLU (thread owns ff column j = tid) ---
    {
        const int j = tid;
        float a2[16];
#pragma unroll
        for (int r = 0; r < 16; ++r) a2[r] = 0.f;
        for (int d0 = 0; d0 < 128; d0 += 4) {
            float w0 = wff1T[(d0 + 0) * 256 + j];
            float w1 = wff1T[(d0 + 1) * 256 + j];
            float w2 = wff1T[(d0 + 2) * 256 + j];
            float w3 = wff1T[(d0 + 3) * 256 + j];
#pragma unroll
            for (int r = 0; r < 16; ++r) {
                float4 h4 = *reinterpret_cast<const float4*>(&Hb[r * 128 + d0]);
                a2[r] = fmaf(w0, h4.x, a2[r]);
                a2[r] = fmaf(w1, h4.y, a2[r]);
                a2[r] = fmaf(w2, h4.z, a2[r]);
                a2[r] = fmaf(w3, h4.w, a2[r]);
            }
        }
        float bj = bff1[j];
#pragma unroll
        for (int r = 0; r < 16; ++r) F[r * 256 + j] = fmaxf(a2[r] + bj, 0.f);
    }
    __syncthreads();

    // --- FF2 + residual ---
    float a3[8];
#pragma unroll
    for (int r = 0; r < 8; ++r) a3[r] = 0.f;
    for (int d0 = 0; d0 < 256; d0 += 4) {
        float w0 = wff2T[(d0 + 0) * 128 + c];
        float w1 = wff2T[(d0 + 1) * 128 + c];
        float w2 = wff2T[(d0 + 2) * 128 + c];
        float w3 = wff2T[(d0 + 3) * 128 + c];
#pragma unroll
        for (int r = 0; r < 8; ++r) {
            float4 f4 = *reinterpret_cast<const float4*>(&F[(g * 8 + r) * 256 + d0]);
            a3[r] = fmaf(w0, f4.x, a3[r]);
            a3[r] = fmaf(w1, f4.y, a3[r]);
            a3[r] = fmaf(w2, f4.z, a3[r]);
            a3[r] = fmaf(w3, f4.w, a3[r]);
        }
    }
    float bo2 = bff2[c];
#pragma unroll
    for (int r = 0; r < 8; ++r) {
        int row = g * 8 + r;
        A[row * 128 + c] = a3[r] + bo2 + Hb[row * 128 + c];   // h1 + ff
    }
    __syncthreads();

    ln_stats(A, mu_s, rs_s, tid);
    __syncthreads();
    float g2c = g2[c], b2c = b2[c];
#pragma unroll
    for (int r = 0; r < 8; ++r) {
        int row = g * 8 + r;
        float nm = nmask[row0 + row];
        float v = (A[row * 128 + c] - mu_s[row]) * rs_s[row] * g2c + b2c;
        out[(row0 + row) * 128 + c] = v * nm;
    }
}

extern "C" void kernel_launch(void* const* d_in, const int* in_sizes, int n_in,
                              void* d_out, int out_size, void* d_ws, size_t ws_size,
                              hipStream_t stream) {
    const float* h = (const float*)d_in[0];
    const float* bias = (const float*)d_in[1];
    const float* nmask = (const float*)d_in[2];
    const void* smask = d_in[3];                 // bool -> byte or int32 (detected)
    const float* w_qkv = (const float*)d_in[4];
    const float* b_qkv = (const float*)d_in[5];
    const float* w_out = (const float*)d_in[6];
    const float* b_out = (const float*)d_in[7];
    const float* w_ff1 = (const float*)d_in[8];
    const float* b_ff1 = (const float*)d_in[9];
    const float* w_ff2 = (const float*)d_in[10];
    const float* b_ff2 = (const float*)d_in[11];
    const float* g1 = (const float*)d_in[12];
    const float* b1 = (const float*)d_in[13];
    const float* g2 = (const float*)d_in[14];
    const float* b2 = (const float*)d_in[15];
    float* out = (float*)d_out;

    char* wsb = (char*)d_ws;
    float* aoutw = (float*)wsb;                               // 4 MB
    unsigned short* qb  = (unsigned short*)(wsb + (4 << 20)); // 2 MB
    unsigned short* kbm = (unsigned short*)(wsb + (6 << 20)); // 2 MB
    unsigned short* vtb = (unsigned short*)(wsb + (8 << 20)); // 2 MB
    unsigned int* cbits = (unsigned int*)(wsb + (10 << 20));  // 2 MB
    unsigned int* nmb   = (unsigned int*)(wsb + (12 << 20));  // 1 KB
    float* wqkvT = (float*)(wsb + (12 << 20) + 4096);         // 192 KB
    float* woutT = wqkvT + 384 * 128;
    float* wff1T = woutT + 128 * 128;
    float* wff2T = wff1T + 256 * 128;
    int* smflag = (int*)(wff2T + 128 * 256);

    transpose_prep_kernel<<<514, 256, 0, stream>>>(w_qkv, w_out, w_ff1, w_ff2,
                                                   wqkvT, woutT, wff1T, wff2T,
                                                   (const unsigned int*)smask, smflag,
                                                   nmask, nmb);
    mask_prep_kernel<<<2048, 256, 0, stream>>>((const unsigned char*)smask, smflag, nmb, cbits);
    qkv_kernel<<<512, 384, 0, stream>>>(h, wqkvT, b_qkv, qb, kbm, vtb);
    attn_kernel<<<2048, 128, 0, stream>>>(qb, kbm, vtb, bias, cbits, nmask, aoutw);
    epilogue_kernel<<<512, 256, 0, stream>>>(aoutw, h, woutT, b_out, wff1T, b_ff1,
                                             wff2T, b_ff2, g1, b1, g2, b2, nmask, out);
}

// Round 15
// 165.719 us; speedup vs baseline: 1.1543x; 1.1543x over previous
//
#include <hip/hip_runtime.h>
#include <math.h>

#define NEG_INF (-1e9f)
#define EPS 1e-5f

typedef __attribute__((ext_vector_type(8))) short short8;
typedef __attribute__((ext_vector_type(4))) float floatx4;

__device__ __forceinline__ unsigned short f2bf(float x) {
    union { float f; unsigned u; } v; v.f = x;
    unsigned r = v.u + 0x7fffu + ((v.u >> 16) & 1u);
    return (unsigned short)(r >> 16);
}

// async global->LDS, 16B per lane: LDS dest = wave-uniform base (+lane*16 by HW),
// global src per-lane (enables source pre-swizzle for swizzled LDS layouts).
__device__ __forceinline__ void gl2lds16(const void* g, void* l) {
    __builtin_amdgcn_global_load_lds(
        (const __attribute__((address_space(1))) unsigned int*)g,
        (__attribute__((address_space(3))) unsigned int*)l, 16, 0, 0);
}

// ---------------- weight transposes + mask-storage detect + node-mask pack ----------------
__global__ void transpose_prep_kernel(const float* __restrict__ w_qkv, const float* __restrict__ w_out,
                                      const float* __restrict__ w_ff1, const float* __restrict__ w_ff2,
                                      float* __restrict__ wqkvT, float* __restrict__ woutT,
                                      float* __restrict__ wff1T, float* __restrict__ wff2T,
                                      const unsigned int* __restrict__ sm, int* __restrict__ flag,
                                      const float* __restrict__ nm, unsigned int* __restrict__ nmb) {
    if (blockIdx.x < 512) {
        int idx = blockIdx.x * 256 + threadIdx.x;        // 131072 total
        if (idx < 49152) {
            int r = idx / 128, c = idx % 128;
            wqkvT[c * 384 + r] = w_qkv[idx];
        } else if (idx < 65536) {
            int i = idx - 49152; int r = i / 128, c = i % 128;
            woutT[c * 128 + r] = w_out[i];
        } else if (idx < 98304) {
            int i = idx - 65536; int r = i / 128, c = i % 128;
            wff1T[c * 256 + r] = w_ff1[i];
        } else {
            int i = idx - 98304; int r = i / 256, c = i % 256;
            wff2T[c * 128 + r] = w_ff2[i];
        }
    } else if (blockIdx.x == 512) {
        __shared__ int bad;
        if (threadIdx.x == 0) bad = 0;
        __syncthreads();
        for (int i = threadIdx.x; i < 4096; i += 256) {
            if (sm[i] > 1u) bad = 1;   // impossible for int32 bool storage
        }
        __syncthreads();
        if (threadIdx.x == 0) *flag = bad;   // 1 -> byte storage, 0 -> int32
    } else {
        const int t = threadIdx.x;            // 256 = 4 b * 64 words
        const int b = t >> 6, w32 = t & 63;
        unsigned u = 0;
#pragma unroll
        for (int j = 0; j < 32; ++j)
            u |= (nm[b * 2048 + w32 * 32 + j] > 0.f ? 1u : 0u) << j;
        nmb[t] = u;
    }
}

// ---------------- combined key-mask bits: cbits[(b*2048+q)*64 + k/32] ----------------
__global__ void mask_prep_kernel(const unsigned char* __restrict__ smraw,
                                 const int* __restrict__ flag,
                                 const unsigned int* __restrict__ nmb,
                                 unsigned int* __restrict__ cbits) {
    const int idx = blockIdx.x * 256 + threadIdx.x;   // 524288 total
    const int b = idx >> 17;
    const int q = (idx >> 6) & 2047;
    const int w32 = idx & 63;
    unsigned u = 0;
    if (*flag) {   // byte storage
        const uint4* p = reinterpret_cast<const uint4*>(
            smraw + (size_t)(b * 2048 + q) * 2048 + w32 * 32);
        uint4 a = p[0], c = p[1];
        unsigned wd0 = a.x, wd1 = a.y, wd2 = a.z, wd3 = a.w;
        unsigned wd4 = c.x, wd5 = c.y, wd6 = c.z, wd7 = c.w;
#define BYTES4(v, sh) \
        u |= ((v) & 0xffu ? 1u : 0u) << (sh); \
        u |= ((v) & 0xff00u ? 1u : 0u) << ((sh) + 1); \
        u |= ((v) & 0xff0000u ? 1u : 0u) << ((sh) + 2); \
        u |= ((v) & 0xff000000u ? 1u : 0u) << ((sh) + 3);
        BYTES4(wd0, 0) BYTES4(wd1, 4) BYTES4(wd2, 8) BYTES4(wd3, 12)
        BYTES4(wd4, 16) BYTES4(wd5, 20) BYTES4(wd6, 24) BYTES4(wd7, 28)
#undef BYTES4
    } else {       // int32 storage
        const uint4* p = reinterpret_cast<const uint4*>(
            reinterpret_cast<const unsigned int*>(smraw) + (size_t)(b * 2048 + q) * 2048 + w32 * 32);
#pragma unroll
        for (int wi = 0; wi < 8; ++wi) {
            uint4 a = p[wi];
            u |= (a.x ? 1u : 0u) << (wi * 4);
            u |= (a.y ? 1u : 0u) << (wi * 4 + 1);
            u |= (a.z ? 1u : 0u) << (wi * 4 + 2);
            u |= (a.w ? 1u : 0u) << (wi * 4 + 3);
        }
    }
    cbits[idx] = u & nmb[b * 64 + w32];
}

// ---------------- QKV projection -> bf16 Q,K [bh][l][32]; bf16 V^T [bh][d][k] ----------------
// grid: B*L/16 = 512 blocks, block: 384 threads (one per output column)
__global__ void qkv_kernel(const float* __restrict__ h, const float* __restrict__ wT,
                           const float* __restrict__ bqkv,
                           unsigned short* __restrict__ qb, unsigned short* __restrict__ kbm,
                           unsigned short* __restrict__ vtb) {
    __shared__ __align__(16) float hs[16 * 128];
    const int tid = threadIdx.x;
    const int row0 = blockIdx.x * 16;
    for (int i = tid; i < 2048; i += 384) hs[i] = h[row0 * 128 + i];
    __syncthreads();

    const int c = tid;
    float acc[16];
#pragma unroll
    for (int r = 0; r < 16; ++r) acc[r] = 0.f;

    for (int d0 = 0; d0 < 128; d0 += 4) {
        float w0 = wT[(d0 + 0) * 384 + c];
        float w1 = wT[(d0 + 1) * 384 + c];
        float w2 = wT[(d0 + 2) * 384 + c];
        float w3 = wT[(d0 + 3) * 384 + c];
#pragma unroll
        for (int r = 0; r < 16; ++r) {
            float4 h4 = *reinterpret_cast<const float4*>(&hs[r * 128 + d0]);
            acc[r] = fmaf(w0, h4.x, acc[r]);
            acc[r] = fmaf(w1, h4.y, acc[r]);
            acc[r] = fmaf(w2, h4.z, acc[r]);
            acc[r] = fmaf(w3, h4.w, acc[r]);
        }
    }
    const int part = c >> 7;        // 0=q 1=k 2=v
    const int cc = c & 127;
    const int head = cc >> 5;
    const int dd = cc & 31;
    const float bias = bqkv[c];
    const float scale = (part == 0) ? 0.17677669529663687f : 1.0f; // 1/sqrt(32) into q
#pragma unroll
    for (int r = 0; r < 16; ++r) {
        int grow = row0 + r;
        int b = grow >> 11, l = grow & 2047;
        int bh = b * 4 + head;
        unsigned short val = f2bf((acc[r] + bias) * scale);
        if (part == 0)      qb[((size_t)bh * 2048 + l) * 32 + dd] = val;
        else if (part == 1) kbm[((size_t)bh * 2048 + l) * 32 + dd] = val;
        else                vtb[((size_t)bh * 32 + dd) * 2048 + l] = val;
    }
}

// ---------------- attention: bf16 MFMA, QBLK=32 x KTILE=64, 4 blocks/CU ----------------
// grid: 1024 blocks (exactly 4/CU resident -> 16 waves/CU, 4 independent barrier
// groups), 256 threads = 4 waves (qsub, khalf). Per tile the BLOCK stages
// K 4KB + V 4KB + bias 8KB (4 gl2lds calls), double-buffered; R11's proven
// counted-vmcnt(4) 2-deep schedule. LDS 37KB. Split-K merge reuses p_lds.
__global__ __launch_bounds__(256, 4) void attn_kernel(
        const unsigned short* __restrict__ qb, const unsigned short* __restrict__ kbm,
        const unsigned short* __restrict__ vtb, const float* __restrict__ bias,
        const unsigned int* __restrict__ cbits, const float* __restrict__ nmask,
        float* __restrict__ aout) {
    __shared__ __align__(16) unsigned short k_lds[2][64 * 32];   // 8 KB
    __shared__ __align__(16) unsigned short v_lds[2][32 * 64];   // 8 KB
    __shared__ __align__(16) float bias_lds[2][32 * 64];         // 16 KB
    __shared__ __align__(16) unsigned short p_lds[4][16 * 40];   // 5 KB (reused for merge)

    const int tid = threadIdx.x;
    const int w = tid >> 6, L = tid & 63;
    const int qsub = w & 1, khalf = w >> 1;
    const int lb = (blockIdx.x & 7) * 128 + (blockIdx.x >> 3);   // bijective, 1024%8==0
    const int bh = lb >> 6, qt = lb & 63;
    const int b = bh >> 2, hh = bh & 3;
    const int q0b = qt * 32;
    const int q = L & 15, g = L >> 4;

    const unsigned short* kb_g = kbm + (size_t)bh * 2048 * 32;
    const unsigned short* vb_g = vtb + (size_t)bh * 32 * 2048;
    const float* bias_q0 = bias + ((size_t)bh * 2048 + q0b) * 2048;
    const short8 qf = *reinterpret_cast<const short8*>(
        qb + ((size_t)bh * 2048 + q0b + qsub * 16 + q) * 32 + g * 8);
    const unsigned int* crow = cbits + (size_t)(b * 2048 + q0b + qsub * 16 + q) * 64;

    // ---- staging source maps (pre-swizzled so linear LDS == swizzled layout) ----
    const int krow = tid >> 2, kc = tid & 3;                    // K: 64 rows x 4 chunks
    const int kf_st = (krow & 3) ^ ((krow >> 2) & 3);
    const int vrow = tid >> 3, vc = tid & 7;                    // V: 32 rows x 8 chunks
    const int brow0 = tid >> 4, bc = tid & 15;                  // bias: 2x16 rows x 16 chunks

    auto stage = [&](int buf, int kt) {
        const int k0 = kt * 64;
        gl2lds16(kb_g + (size_t)(k0 + krow) * 32 + ((kc ^ kf_st) << 3),
                 (char*)(&k_lds[buf][0]) + w * 1024);
        gl2lds16(vb_g + (size_t)vrow * 2048 + k0 + ((vc ^ (vrow & 7)) << 3),
                 (char*)(&v_lds[buf][0]) + w * 1024);
#pragma unroll
        for (int i = 0; i < 2; ++i) {
            const int row = i * 16 + brow0;
            gl2lds16(bias_q0 + (size_t)row * 2048 + k0 + ((bc ^ (row & 7)) << 2),
                     (char*)(&bias_lds[buf][0]) + i * 4096 + w * 1024);
        }
    };

    // prologue: 2 tiles issued (8 calls); retire tile0's 4, keep tile1's 4 in flight
    stage(0, 0);
    stage(1, 1);
    asm volatile("s_waitcnt vmcnt(4)" ::: "memory");
    __builtin_amdgcn_s_barrier();

    float mrun = -3.0e38f, lrun = 0.f;
    floatx4 o0 = {0.f, 0.f, 0.f, 0.f}, o1 = {0.f, 0.f, 0.f, 0.f};
    const floatx4 zacc = {0.f, 0.f, 0.f, 0.f};
    unsigned short* pl = &p_lds[w][q * 40];

    // ---- read-side swizzled offsets (constant per lane) ----
    const int r0k = khalf * 32 + q;
    const int fk = (q & 3) ^ ((q >> 2) & 3);               // same for rows r0k and r0k+16
    const int koff0 = r0k * 64 + ((g ^ fk) << 4);
    const int koff1 = (r0k + 16) * 64 + ((g ^ fk) << 4);
    const int vch = khalf * 4 + g;
    const int voff0 = q * 128 + ((vch ^ (q & 7)) << 4);
    const int voff1 = (16 + q) * 128 + ((vch ^ (q & 7)) << 4);
    const int R = qsub * 16 + q;
    const int j0 = khalf * 8 + g;
    const int boff0 = R * 256 + (((j0    ) ^ (R & 7)) << 4);
    const int boff1 = R * 256 + (((j0 + 4) ^ (R & 7)) << 4);

    for (int t = 0; t < 32; ++t) {
        const int cur = t & 1;

        // ---- fragments from LDS ----
        const char* kl = (const char*)(&k_lds[cur][0]);
        short8 kf0 = *reinterpret_cast<const short8*>(kl + koff0);
        short8 kf1 = *reinterpret_cast<const short8*>(kl + koff1);
        const char* vl = (const char*)(&v_lds[cur][0]);
        short8 vf0 = *reinterpret_cast<const short8*>(vl + voff0);
        short8 vf1 = *reinterpret_cast<const short8*>(vl + voff1);
        const char* bl = (const char*)(&bias_lds[cur][0]);
        float4 bq0 = *reinterpret_cast<const float4*>(bl + boff0);
        float4 bq1 = *reinterpret_cast<const float4*>(bl + boff1);
        const unsigned cw = crow[2 * t + khalf];

        // ---- QK^T (2 MFMA: this khalf's k' 0..15, 16..31) ----
        floatx4 rr0 = __builtin_amdgcn_mfma_f32_16x16x32_bf16(kf0, qf, zacc, 0, 0, 0);
        floatx4 rr1 = __builtin_amdgcn_mfma_f32_16x16x32_bf16(kf1, qf, zacc, 0, 0, 0);
        float s[8];
        s[0] = rr0[0]; s[1] = rr0[1]; s[2] = rr0[2]; s[3] = rr0[3];
        s[4] = rr1[0]; s[5] = rr1[1]; s[6] = rr1[2]; s[7] = rr1[3];
        float bvv[8];
        bvv[0] = bq0.x; bvv[1] = bq0.y; bvv[2] = bq0.z; bvv[3] = bq0.w;
        bvv[4] = bq1.x; bvv[5] = bq1.y; bvv[6] = bq1.z; bvv[7] = bq1.w;
#pragma unroll
        for (int i = 0; i < 8; ++i) {
            const int mm = i >> 2, reg = i & 3;
            const int sh = mm * 16 + 4 * g + reg;   // k' within this khalf's 32
            const bool keep = (cw >> sh) & 1;
            s[i] = keep ? (s[i] + bvv[i]) : NEG_INF;
        }
        // ---- online softmax (in-lane 8 + 2 shfl across g) ----
        float tm = s[0];
#pragma unroll
        for (int i = 1; i < 8; ++i) tm = fmaxf(tm, s[i]);
        tm = fmaxf(tm, __shfl_xor(tm, 16));
        tm = fmaxf(tm, __shfl_xor(tm, 32));
        const float mn = fmaxf(mrun, tm);
        const float f = __expf(mrun - mn);
        mrun = mn;
        float p[8], ts = 0.f;
#pragma unroll
        for (int i = 0; i < 8; ++i) { p[i] = __expf(s[i] - mn); ts += p[i]; }
        ts += __shfl_xor(ts, 16);
        ts += __shfl_xor(ts, 32);
        lrun = lrun * f + ts;
        o0 *= f; o1 *= f;
        // ---- pack P -> bf16, stage in wave-private LDS (stride 40 shorts) ----
        {
            unsigned u0 = (unsigned)f2bf(p[0]) | ((unsigned)f2bf(p[1]) << 16);
            unsigned u1 = (unsigned)f2bf(p[2]) | ((unsigned)f2bf(p[3]) << 16);
            unsigned u2 = (unsigned)f2bf(p[4]) | ((unsigned)f2bf(p[5]) << 16);
            unsigned u3 = (unsigned)f2bf(p[6]) | ((unsigned)f2bf(p[7]) << 16);
            *reinterpret_cast<unsigned int*>(pl + 4 * g) = u0;
            *reinterpret_cast<unsigned int*>(pl + 4 * g + 2) = u1;
            *reinterpret_cast<unsigned int*>(pl + 16 + 4 * g) = u2;
            *reinterpret_cast<unsigned int*>(pl + 16 + 4 * g + 2) = u3;
        }
        // ---- PV (2 MFMA over this khalf's K=32) ----
        short8 pb = *reinterpret_cast<const short8*>(pl + 8 * g);
        o0 = __builtin_amdgcn_mfma_f32_16x16x32_bf16(vf0, pb, o0, 0, 0, 0);
        o1 = __builtin_amdgcn_mfma_f32_16x16x32_bf16(vf1, pb, o1, 0, 0, 0);

        // ---- pipeline advance (R11 cadence): restage freed buffer with t+2 ----
        if (t < 31) {
            __builtin_amdgcn_s_barrier();          // all waves done with buf cur
            if (t + 2 < 32) {
                stage(cur, t + 2);                 // 4 async calls into freed buffer
                asm volatile("s_waitcnt vmcnt(4)" ::: "memory");  // t+1's 4 retired
            } else {
                asm volatile("s_waitcnt vmcnt(0)" ::: "memory");  // tail drain
            }
            __builtin_amdgcn_s_barrier();
        }
    }

    // ---- split-K merge (reuse p_lds as merge buffer) ----
    __syncthreads();   // all waves done with p_lds
    float* mb = reinterpret_cast<float*>(&p_lds[0][0]);   // 2*64*10 floats = 5120 B
    if (khalf == 1) {
        float* dst = mb + (qsub * 64 + L) * 10;
        dst[0] = mrun; dst[1] = lrun;
        dst[2] = o0[0]; dst[3] = o0[1]; dst[4] = o0[2]; dst[5] = o0[3];
        dst[6] = o1[0]; dst[7] = o1[1]; dst[8] = o1[2]; dst[9] = o1[3];
    }
    __syncthreads();
    if (khalf == 0) {
        const float* src = mb + (qsub * 64 + L) * 10;
        const float m2 = src[0], l2 = src[1];
        const float mm = fmaxf(mrun, m2);
        const float f1 = __expf(mrun - mm), f2 = __expf(m2 - mm);
        const float l = lrun * f1 + l2 * f2;
        const int qrow = q0b + qsub * 16 + q;
        const float nmq = nmask[b * 2048 + qrow];
        const float inv = (nmq > 0.f) ? (1.f / l) : 0.f;
        const float a1 = f1 * inv, a2 = f2 * inv;
        float* op = aout + ((size_t)b * 2048 + qrow) * 128 + hh * 32 + g * 4;
        *reinterpret_cast<float4*>(op) = make_float4(
            o0[0] * a1 + src[2] * a2, o0[1] * a1 + src[3] * a2,
            o0[2] * a1 + src[4] * a2, o0[3] * a1 + src[5] * a2);
        *reinterpret_cast<float4*>(op + 16) = make_float4(
            o1[0] * a1 + src[6] * a2, o1[1] * a1 + src[7] * a2,
            o1[2] * a1 + src[8] * a2, o1[3] * a1 + src[9] * a2);
    }
}

// ---------------- LN stats helper (16 rows x 128 cols in LDS) ----------------
__device__ __forceinline__ void ln_stats(const float* buf, float* mu_s, float* rs_s, int tid) {
    int row = tid >> 4, sl = tid & 15;
    float4 x0 = *reinterpret_cast<const float4*>(&buf[row * 128 + sl * 8]);
    float4 x1 = *reinterpret_cast<const float4*>(&buf[row * 128 + sl * 8 + 4]);
    float sum = x0.x + x0.y + x0.z + x0.w + x1.x + x1.y + x1.z + x1.w;
    float sq = x0.x * x0.x + x0.y * x0.y + x0.z * x0.z + x0.w * x0.w +
               x1.x * x1.x + x1.y * x1.y + x1.z * x1.z + x1.w * x1.w;
#pragma unroll
    for (int off = 8; off > 0; off >>= 1) {
        sum += __shfl_xor(sum, off);
        sq += __shfl_xor(sq, off);
    }
    if (sl == 0) {
        float mu = sum * (1.f / 128.f);
        float var = sq * (1.f / 128.f) - mu * mu;
        mu_s[row] = mu;
        rs_s[row] = rsqrtf(var + EPS);
    }
}

// ---------------- fused epilogue: out-proj + res + LN1 + FFN + res + LN2 + mask ----------------
// grid: B*L/16 = 512 blocks, block: 256 threads
__global__ void epilogue_kernel(const float* __restrict__ aout, const float* __restrict__ h,
                                const float* __restrict__ woutT, const float* __restrict__ bout,
                                const float* __restrict__ wff1T, const float* __restrict__ bff1,
                                const float* __restrict__ wff2T, const float* __restrict__ bff2,
                                const float* __restrict__ g1, const float* __restrict__ b1,
                                const float* __restrict__ g2, const float* __restrict__ b2,
                                const float* __restrict__ nmask, float* __restrict__ out) {
    __shared__ __align__(16) float A[16 * 128];
    __shared__ __align__(16) float Hb[16 * 128];
    __shared__ __align__(16) float F[16 * 256];
    __shared__ float mu_s[16], rs_s[16];

    const int tid = threadIdx.x;
    const int row0 = blockIdx.x * 16;
    for (int i = tid; i < 2048; i += 256) {
        A[i] = aout[row0 * 128 + i];
        Hb[i] = h[row0 * 128 + i];
    }
    __syncthreads();

    const int g = tid >> 7, c = tid & 127;

    // --- out-projection ---
    float acc[8];
#pragma unroll
    for (int r = 0; r < 8; ++r) acc[r] = 0.f;
    for (int d0 = 0; d0 < 128; d0 += 4) {
        float w0 = woutT[(d0 + 0) * 128 + c];
        float w1 = woutT[(d0 + 1) * 128 + c];
        float w2 = woutT[(d0 + 2) * 128 + c];
        float w3 = woutT[(d0 + 3) * 128 + c];
#pragma unroll
        for (int r = 0; r < 8; ++r) {
            float4 a4 = *reinterpret_cast<const float4*>(&A[(g * 8 + r) * 128 + d0]);
            acc[r] = fmaf(w0, a4.x, acc[r]);
            acc[r] = fmaf(w1, a4.y, acc[r]);
            acc[r] = fmaf(w2, a4.z, acc[r]);
            acc[r] = fmaf(w3, a4.w, acc[r]);
        }
    }
    float bo = bout[c];
#pragma unroll
    for (int r = 0; r < 8; ++r) {
        int row = g * 8 + r;
        Hb[row * 128 + c] += acc[r] + bo;   // h + attn_out
    }
    __syncthreads();

    ln_stats(Hb, mu_s, rs_s, tid);
    __syncthreads();
    float g1c = g1[c], b1c = b1[c];
#pragma unroll
    for (int r = 0; r < 8; ++r) {
        int row = g * 8 + r;
        float v = (Hb[row * 128 + c] - mu_s[row]) * rs_s[row] * g1c + b1c;
        Hb[row * 128 + c] = v;              // h1
    }
    __syncthreads();

    // --- FF1 + ReLU (thread owns ff column j = tid) ---
    {
        const int j = tid;
        float a2[16];
#pragma unroll
        for (int r = 0; r < 16; ++r) a2[r] = 0.f;
        for (int d0 = 0; d0 < 128; d0 += 4) {
            float w0 = wff1T[(d0 + 0) * 256 + j];
            float w1 = wff1T[(d0 + 1) * 256 + j];
            float w2 = wff1T[(d0 + 2) * 256 + j];
            float w3 = wff1T[(d0 + 3) * 256 + j];
#pragma unroll
            for (int r = 0; r < 16; ++r) {
                float4 h4 = *reinterpret_cast<const float4*>(&Hb[r * 128 + d0]);
                a2[r] = fmaf(w0, h4.x, a2[r]);
                a2[r] = fmaf(w1, h4.y, a2[r]);
                a2[r] = fmaf(w2, h4.z, a2[r]);
                a2[r] = fmaf(w3, h4.w, a2[r]);
            }
        }
        float bj = bff1[j];
#pragma unroll
        for (int r = 0; r < 16; ++r) F[r * 256 + j] = fmaxf(a2[r] + bj, 0.f);
    }
    __syncthreads();

    // --- FF2 + residual ---
    float a3[8];
#pragma unroll
    for (int r = 0; r < 8; ++r) a3[r] = 0.f;
    for (int d0 = 0; d0 < 256; d0 += 4) {
        float w0 = wff2T[(d0 + 0) * 128 + c];
        float w1 = wff2T[(d0 + 1) * 128 + c];
        float w2 = wff2T[(d0 + 2) * 128 + c];
        float w3 = wff2T[(d0 + 3) * 128 + c];
#pragma unroll
        for (int r = 0; r < 8; ++r) {
            float4 f4 = *reinterpret_cast<const float4*>(&F[(g * 8 + r) * 256 + d0]);
            a3[r] = fmaf(w0, f4.x, a3[r]);
            a3[r] = fmaf(w1, f4.y, a3[r]);
            a3[r] = fmaf(w2, f4.z, a3[r]);
            a3[r] = fmaf(w3, f4.w, a3[r]);
        }
    }
    float bo2 = bff2[c];
#pragma unroll
    for (int r = 0; r < 8; ++r) {
        int row = g * 8 + r;
        A[row * 128 + c] = a3[r] + bo2 + Hb[row * 128 + c];   // h1 + ff
    }
    __syncthreads();

    ln_stats(A, mu_s, rs_s, tid);
    __syncthreads();
    float g2c = g2[c], b2c = b2[c];
#pragma unroll
    for (int r = 0; r < 8; ++r) {
        int row = g * 8 + r;
        float nm = nmask[row0 + row];
        float v = (A[row * 128 + c] - mu_s[row]) * rs_s[row] * g2c + b2c;
        out[(row0 + row) * 128 + c] = v * nm;
    }
}

extern "C" void kernel_launch(void* const* d_in, const int* in_sizes, int n_in,
                              void* d_out, int out_size, void* d_ws, size_t ws_size,
                              hipStream_t stream) {
    const float* h = (const float*)d_in[0];
    const float* bias = (const float*)d_in[1];
    const float* nmask = (const float*)d_in[2];
    const void* smask = d_in[3];                 // bool -> byte or int32 (detected)
    const float* w_qkv = (const float*)d_in[4];
    const float* b_qkv = (const float*)d_in[5];
    const float* w_out = (const float*)d_in[6];
    const float* b_out = (const float*)d_in[7];
    const float* w_ff1 = (const float*)d_in[8];
    const float* b_ff1 = (const float*)d_in[9];
    const float* w_ff2 = (const float*)d_in[10];
    const float* b_ff2 = (const float*)d_in[11];
    const float* g1 = (const float*)d_in[12];
    const float* b1 = (const float*)d_in[13];
    const float* g2 = (const float*)d_in[14];
    const float* b2 = (const float*)d_in[15];
    float* out = (float*)d_out;

    char* wsb = (char*)d_ws;
    float* aoutw = (float*)wsb;                               // 4 MB
    unsigned short* qb  = (unsigned short*)(wsb + (4 << 20)); // 2 MB
    unsigned short* kbm = (unsigned short*)(wsb + (6 << 20)); // 2 MB
    unsigned short* vtb = (unsigned short*)(wsb + (8 << 20)); // 2 MB
    unsigned int* cbits = (unsigned int*)(wsb + (10 << 20));  // 2 MB
    unsigned int* nmb   = (unsigned int*)(wsb + (12 << 20));  // 1 KB
    float* wqkvT = (float*)(wsb + (12 << 20) + 4096);         // 192 KB
    float* woutT = wqkvT + 384 * 128;
    float* wff1T = woutT + 128 * 128;
    float* wff2T = wff1T + 256 * 128;
    int* smflag = (int*)(wff2T + 128 * 256);

    transpose_prep_kernel<<<514, 256, 0, stream>>>(w_qkv, w_out, w_ff1, w_ff2,
                                                   wqkvT, woutT, wff1T, wff2T,
                                                   (const unsigned int*)smask, smflag,
                                                   nmask, nmb);
    mask_prep_kernel<<<2048, 256, 0, stream>>>((const unsigned char*)smask, smflag, nmb, cbits);
    qkv_kernel<<<512, 384, 0, stream>>>(h, wqkvT, b_qkv, qb, kbm, vtb);
    attn_kernel<<<1024, 256, 0, stream>>>(qb, kbm, vtb, bias, cbits, nmask, aoutw);
    epilogue_kernel<<<512, 256, 0, stream>>>(aoutw, h, woutT, b_out, wff1T, b_ff1,
                                             wff2T, b_ff2, g1, b1, g2, b2, nmask, out);
}

// Round 16
// 162.865 us; speedup vs baseline: 1.1745x; 1.0175x over previous
//
#include <hip/hip_runtime.h>
#include <math.h>

#define NEG_INF (-1e9f)
#define EPS 1e-5f

typedef __attribute__((ext_vector_type(8))) short short8;
typedef __attribute__((ext_vector_type(4))) float floatx4;

__device__ __forceinline__ unsigned short f2bf(float x) {
    union { float f; unsigned u; } v; v.f = x;
    unsigned r = v.u + 0x7fffu + ((v.u >> 16) & 1u);
    return (unsigned short)(r >> 16);
}

// async global->LDS, 16B per lane: LDS dest = wave-uniform base (+lane*16 by HW),
// global src per-lane (enables source pre-swizzle for swizzled LDS layouts).
__device__ __forceinline__ void gl2lds16(const void* g, void* l) {
    __builtin_amdgcn_global_load_lds(
        (const __attribute__((address_space(1))) unsigned int*)g,
        (__attribute__((address_space(3))) unsigned int*)l, 16, 0, 0);
}

// ---------------- fused prep: weight transposes (blocks 0-511) + combined key-mask
// bits (blocks 512-2559, flag & node-mask bits inlined per block) ----------------
__global__ void prep_kernel(const float* __restrict__ w_qkv, const float* __restrict__ w_out,
                            const float* __restrict__ w_ff1, const float* __restrict__ w_ff2,
                            float* __restrict__ wqkvT, float* __restrict__ woutT,
                            float* __restrict__ wff1T, float* __restrict__ wff2T,
                            const unsigned char* __restrict__ smraw,
                            const float* __restrict__ nm, unsigned int* __restrict__ cbits) {
    if (blockIdx.x < 512) {
        int idx = blockIdx.x * 256 + threadIdx.x;        // 131072 total
        if (idx < 49152) {
            int r = idx / 128, c = idx % 128;
            wqkvT[c * 384 + r] = w_qkv[idx];
        } else if (idx < 65536) {
            int i = idx - 49152; int r = i / 128, c = i % 128;
            woutT[c * 128 + r] = w_out[i];
        } else if (idx < 98304) {
            int i = idx - 65536; int r = i / 128, c = i % 128;
            wff1T[c * 256 + r] = w_ff1[i];
        } else {
            int i = idx - 98304; int r = i / 256, c = i % 256;
            wff2T[c * 128 + r] = w_ff2[i];
        }
        return;
    }
    // ---- mask blocks: detect storage mode per block (L2/L3-hot scan) ----
    __shared__ int bad;
    if (threadIdx.x == 0) bad = 0;
    __syncthreads();
    const unsigned int* sm32v = reinterpret_cast<const unsigned int*>(smraw);
    for (int i = threadIdx.x; i < 4096; i += 256) {
        if (sm32v[i] > 1u) bad = 1;   // impossible for int32 bool storage
    }
    __syncthreads();
    const int bytemode = bad;

    const int idx = (blockIdx.x - 512) * 256 + threadIdx.x;   // 524288 total
    const int b = idx >> 17;
    const int q = (idx >> 6) & 2047;
    const int w32 = idx & 63;
    unsigned u = 0;
    if (bytemode) {   // byte storage
        const uint4* p = reinterpret_cast<const uint4*>(
            smraw + (size_t)(b * 2048 + q) * 2048 + w32 * 32);
        uint4 a = p[0], c = p[1];
        unsigned wd0 = a.x, wd1 = a.y, wd2 = a.z, wd3 = a.w;
        unsigned wd4 = c.x, wd5 = c.y, wd6 = c.z, wd7 = c.w;
#define BYTES4(v, sh) \
        u |= ((v) & 0xffu ? 1u : 0u) << (sh); \
        u |= ((v) & 0xff00u ? 1u : 0u) << ((sh) + 1); \
        u |= ((v) & 0xff0000u ? 1u : 0u) << ((sh) + 2); \
        u |= ((v) & 0xff000000u ? 1u : 0u) << ((sh) + 3);
        BYTES4(wd0, 0) BYTES4(wd1, 4) BYTES4(wd2, 8) BYTES4(wd3, 12)
        BYTES4(wd4, 16) BYTES4(wd5, 20) BYTES4(wd6, 24) BYTES4(wd7, 28)
#undef BYTES4
    } else {          // int32 storage
        const uint4* p = reinterpret_cast<const uint4*>(
            sm32v + (size_t)(b * 2048 + q) * 2048 + w32 * 32);
#pragma unroll
        for (int wi = 0; wi < 8; ++wi) {
            uint4 a = p[wi];
            u |= (a.x ? 1u : 0u) << (wi * 4);
            u |= (a.y ? 1u : 0u) << (wi * 4 + 1);
            u |= (a.z ? 1u : 0u) << (wi * 4 + 2);
            u |= (a.w ? 1u : 0u) << (wi * 4 + 3);
        }
    }
    // inline node-mask bits (nm is 32KB, L2-resident)
    unsigned nb = 0;
    const float* nmp = nm + b * 2048 + w32 * 32;
#pragma unroll
    for (int j = 0; j < 32; ++j) nb |= (nmp[j] > 0.f ? 1u : 0u) << j;
    cbits[idx] = u & nb;
}

// ---------------- QKV projection -> bf16 Q,K [bh][l][32]; bf16 V^T [bh][d][k] ----------------
// grid: B*L/16 = 512 blocks, block: 384 threads (one per output column)
__global__ void qkv_kernel(const float* __restrict__ h, const float* __restrict__ wT,
                           const float* __restrict__ bqkv,
                           unsigned short* __restrict__ qb, unsigned short* __restrict__ kbm,
                           unsigned short* __restrict__ vtb) {
    __shared__ __align__(16) float hs[16 * 128];
    const int tid = threadIdx.x;
    const int row0 = blockIdx.x * 16;
    for (int i = tid; i < 2048; i += 384) hs[i] = h[row0 * 128 + i];
    __syncthreads();

    const int c = tid;
    float acc[16];
#pragma unroll
    for (int r = 0; r < 16; ++r) acc[r] = 0.f;

    for (int d0 = 0; d0 < 128; d0 += 4) {
        float w0 = wT[(d0 + 0) * 384 + c];
        float w1 = wT[(d0 + 1) * 384 + c];
        float w2 = wT[(d0 + 2) * 384 + c];
        float w3 = wT[(d0 + 3) * 384 + c];
#pragma unroll
        for (int r = 0; r < 16; ++r) {
            float4 h4 = *reinterpret_cast<const float4*>(&hs[r * 128 + d0]);
            acc[r] = fmaf(w0, h4.x, acc[r]);
            acc[r] = fmaf(w1, h4.y, acc[r]);
            acc[r] = fmaf(w2, h4.z, acc[r]);
            acc[r] = fmaf(w3, h4.w, acc[r]);
        }
    }
    const int part = c >> 7;        // 0=q 1=k 2=v
    const int cc = c & 127;
    const int head = cc >> 5;
    const int dd = cc & 31;
    const float bias = bqkv[c];
    const float scale = (part == 0) ? 0.17677669529663687f : 1.0f; // 1/sqrt(32) into q
#pragma unroll
    for (int r = 0; r < 16; ++r) {
        int grow = row0 + r;
        int b = grow >> 11, l = grow & 2047;
        int bh = b * 4 + head;
        unsigned short val = f2bf((acc[r] + bias) * scale);
        if (part == 0)      qb[((size_t)bh * 2048 + l) * 32 + dd] = val;
        else if (part == 1) kbm[((size_t)bh * 2048 + l) * 32 + dd] = val;
        else                vtb[((size_t)bh * 32 + dd) * 2048 + l] = val;
    }
}

// ---------------- attention (R11 structure, + s_setprio around compute) ----------------
// grid: 512 blocks (2/CU resident), block: 256 threads = 4 waves, 64 q-rows/block.
// Per 64-k tile the BLOCK stages (async, zero VGPR): K 4KB + V^T 4KB + bias 16KB.
// Counted-vmcnt schedule: raw s_barrier + s_waitcnt vmcnt(6) — next-next tile's
// 6 loads stay in flight across the barrier; never drain to 0 in the main loop.
__global__ __launch_bounds__(256, 2) void attn_kernel(
        const unsigned short* __restrict__ qb, const unsigned short* __restrict__ kbm,
        const unsigned short* __restrict__ vtb, const float* __restrict__ bias,
        const unsigned int* __restrict__ cbits, const float* __restrict__ nmask,
        float* __restrict__ aout) {
    __shared__ __align__(16) unsigned short k_lds[2][64 * 32];   // 2 x 4 KB
    __shared__ __align__(16) unsigned short v_lds[2][32 * 64];   // 2 x 4 KB
    __shared__ __align__(16) float bias_lds[2][64 * 64];         // 2 x 16 KB
    __shared__ __align__(16) unsigned short p_lds[4][16 * 72];   // 9 KB, wave-private

    const int tid = threadIdx.x;
    const int w = tid >> 6, L = tid & 63;
    const int lb = (blockIdx.x & 7) * 64 + (blockIdx.x >> 3);   // bijective, 512%8==0
    const int bh = lb >> 5, qt = lb & 31;
    const int b = bh >> 2, hh = bh & 3;
    const int q0b = qt * 64;                 // block's first q-row
    const int q = L & 15, g = L >> 4;

    const unsigned short* kb_g = kbm + (size_t)bh * 2048 * 32;
    const unsigned short* vb_g = vtb + (size_t)bh * 32 * 2048;
    const float* bias_q0 = bias + ((size_t)bh * 2048 + q0b) * 2048;
    const short8 qf = *reinterpret_cast<const short8*>(
        qb + ((size_t)bh * 2048 + q0b + w * 16 + q) * 32 + g * 8);
    const unsigned int* crow = cbits + (size_t)(b * 2048 + q0b + w * 16 + q) * 64;

    // staging source maps (pre-swizzled so linear LDS == swizzled layout)
    const int r_k = tid >> 2;                                   // K row 0..63
    const size_t k_src0 = (size_t)r_k * 32 + (((tid & 3) ^ (r_k & 3)) << 3);
    const int d_v = tid >> 3;                                   // V^T row 0..31
    const size_t v_src0 = (size_t)d_v * 2048 + (((tid & 7) ^ (d_v & 7)) << 3);
    const int br = tid >> 4;                                    // bias row (mod 16)
    const int bsw = ((tid & 15) ^ br) << 2;                     // swizzled float col

    auto stage = [&](int buf, int kt) {
        const int k0 = kt * 64;
        gl2lds16(kb_g + (size_t)k0 * 32 + k_src0, (char*)(&k_lds[buf][0]) + w * 1024);
        gl2lds16(vb_g + k0 + v_src0, (char*)(&v_lds[buf][0]) + w * 1024);
#pragma unroll
        for (int i = 0; i < 4; ++i)
            gl2lds16(bias_q0 + (size_t)(br + 16 * i) * 2048 + k0 + bsw,
                     (char*)(&bias_lds[buf][0]) + i * 4096 + w * 1024);
    };

    // prologue: 2 tiles in flight, wait for tile 0 only (6 of tile 1 outstanding)
    stage(0, 0);
    stage(1, 1);
    asm volatile("s_waitcnt vmcnt(6)" ::: "memory");
    __builtin_amdgcn_s_barrier();

    float mrun = -3.0e38f, lrun = 0.f;
    floatx4 o0 = {0.f, 0.f, 0.f, 0.f}, o1 = {0.f, 0.f, 0.f, 0.f};
    const floatx4 zacc = {0.f, 0.f, 0.f, 0.f};
    unsigned short* pl = &p_lds[w][q * 72];

    // read-side swizzled offsets (constant per lane)
    const int ksw = (g ^ (q & 3)) << 4;       // K col16 swizzle
    const int vsw0 = ((g) ^ (q & 7)) << 4;    // V col16 (k 0..31)
    const int vsw1 = ((g + 4) ^ (q & 7)) << 4;// V col16 (k 32..63)
    const int brow = (w * 16 + q) * 256;      // bias row byte offset

    for (int t = 0; t < 32; ++t) {
        const int cur = t & 1;

        // ---- fragments from LDS ----
        const char* kl = (const char*)(&k_lds[cur][0]);
        short8 kf0 = *reinterpret_cast<const short8*>(kl + (q     ) * 64 + ksw);
        short8 kf1 = *reinterpret_cast<const short8*>(kl + (16 + q) * 64 + ksw);
        short8 kf2 = *reinterpret_cast<const short8*>(kl + (32 + q) * 64 + ksw);
        short8 kf3 = *reinterpret_cast<const short8*>(kl + (48 + q) * 64 + ksw);
        const char* vl = (const char*)(&v_lds[cur][0]);
        short8 vf00 = *reinterpret_cast<const short8*>(vl + (q     ) * 128 + vsw0);
        short8 vf01 = *reinterpret_cast<const short8*>(vl + (q     ) * 128 + vsw1);
        short8 vf10 = *reinterpret_cast<const short8*>(vl + (16 + q) * 128 + vsw0);
        short8 vf11 = *reinterpret_cast<const short8*>(vl + (16 + q) * 128 + vsw1);
        uint2 cw = *reinterpret_cast<const uint2*>(crow + t * 2);

        __builtin_amdgcn_s_setprio(1);
        // ---- QK^T ----
        float s[16];
        {
            floatx4 r0 = __builtin_amdgcn_mfma_f32_16x16x32_bf16(kf0, qf, zacc, 0, 0, 0);
            floatx4 r1 = __builtin_amdgcn_mfma_f32_16x16x32_bf16(kf1, qf, zacc, 0, 0, 0);
            floatx4 r2 = __builtin_amdgcn_mfma_f32_16x16x32_bf16(kf2, qf, zacc, 0, 0, 0);
            floatx4 r3 = __builtin_amdgcn_mfma_f32_16x16x32_bf16(kf3, qf, zacc, 0, 0, 0);
            s[0] = r0[0]; s[1] = r0[1]; s[2] = r0[2]; s[3] = r0[3];
            s[4] = r1[0]; s[5] = r1[1]; s[6] = r1[2]; s[7] = r1[3];
            s[8] = r2[0]; s[9] = r2[1]; s[10] = r2[2]; s[11] = r2[3];
            s[12] = r3[0]; s[13] = r3[1]; s[14] = r3[2]; s[15] = r3[3];
        }
        // ---- bias fragments from LDS (swizzled rows -> 2-way, free) ----
        const char* bl = (const char*)(&bias_lds[cur][0]);
        float4 bq0 = *reinterpret_cast<const float4*>(bl + brow + (((0 + g) ^ q) << 4));
        float4 bq1 = *reinterpret_cast<const float4*>(bl + brow + (((4 + g) ^ q) << 4));
        float4 bq2 = *reinterpret_cast<const float4*>(bl + brow + (((8 + g) ^ q) << 4));
        float4 bq3 = *reinterpret_cast<const float4*>(bl + brow + (((12 + g) ^ q) << 4));
        float bvv[16];
        bvv[0] = bq0.x; bvv[1] = bq0.y; bvv[2] = bq0.z; bvv[3] = bq0.w;
        bvv[4] = bq1.x; bvv[5] = bq1.y; bvv[6] = bq1.z; bvv[7] = bq1.w;
        bvv[8] = bq2.x; bvv[9] = bq2.y; bvv[10] = bq2.z; bvv[11] = bq2.w;
        bvv[12] = bq3.x; bvv[13] = bq3.y; bvv[14] = bq3.z; bvv[15] = bq3.w;
#pragma unroll
        for (int i = 0; i < 16; ++i) {
            const int mm = i >> 2, reg = i & 3;
            const unsigned word = (mm < 2) ? cw.x : cw.y;
            const int sh = 16 * (mm & 1) + 4 * g + reg;
            const bool keep = (word >> sh) & 1;
            s[i] = keep ? (s[i] + bvv[i]) : NEG_INF;
        }
        // ---- online softmax (in-lane 16 + 2 shfl) ----
        float tm = s[0];
#pragma unroll
        for (int i = 1; i < 16; ++i) tm = fmaxf(tm, s[i]);
        tm = fmaxf(tm, __shfl_xor(tm, 16));
        tm = fmaxf(tm, __shfl_xor(tm, 32));
        const float mn = fmaxf(mrun, tm);
        const float f = __expf(mrun - mn);
        mrun = mn;
        float p[16], ts = 0.f;
#pragma unroll
        for (int i = 0; i < 16; ++i) { p[i] = __expf(s[i] - mn); ts += p[i]; }
        ts += __shfl_xor(ts, 16);
        ts += __shfl_xor(ts, 32);
        lrun = lrun * f + ts;
        o0 *= f; o1 *= f;
        // ---- pack P -> bf16, stage in wave-private LDS row (stride 72) ----
#pragma unroll
        for (int mm = 0; mm < 4; ++mm) {
            unsigned u0 = (unsigned)f2bf(p[4 * mm]) | ((unsigned)f2bf(p[4 * mm + 1]) << 16);
            unsigned u1 = (unsigned)f2bf(p[4 * mm + 2]) | ((unsigned)f2bf(p[4 * mm + 3]) << 16);
            *reinterpret_cast<unsigned int*>(pl + 16 * mm + 4 * g) = u0;
            *reinterpret_cast<unsigned int*>(pl + 16 * mm + 4 * g + 2) = u1;
        }
        // ---- PV: B-frag = own row's 8 consecutive k ----
        short8 pb0 = *reinterpret_cast<const short8*>(pl + g * 8);
        short8 pb1 = *reinterpret_cast<const short8*>(pl + 32 + g * 8);
        o0 = __builtin_amdgcn_mfma_f32_16x16x32_bf16(vf00, pb0, o0, 0, 0, 0);
        o0 = __builtin_amdgcn_mfma_f32_16x16x32_bf16(vf01, pb1, o0, 0, 0, 0);
        o1 = __builtin_amdgcn_mfma_f32_16x16x32_bf16(vf10, pb0, o1, 0, 0, 0);
        o1 = __builtin_amdgcn_mfma_f32_16x16x32_bf16(vf11, pb1, o1, 0, 0, 0);
        __builtin_amdgcn_s_setprio(0);

        // ---- pipeline advance: free buf[cur], restage it with tile t+2 ----
        if (t < 31) {
            __builtin_amdgcn_s_barrier();          // all waves done reading buf[cur]
            if (t + 2 < 32) {
                stage(cur, t + 2);                 // 6 async loads into freed buffer
                asm volatile("s_waitcnt vmcnt(6)" ::: "memory");  // t+1's loads retired
            } else {
                asm volatile("s_waitcnt vmcnt(0)" ::: "memory");  // tail: drain last tile
            }
            __builtin_amdgcn_s_barrier();          // everyone's t+1 data visible
        }
    }

    // ---- epilogue: normalize, query mask, write ----
    const int qrow = q0b + w * 16 + q;
    const float nmq = nmask[b * 2048 + qrow];
    const float inv = (nmq > 0.f) ? (1.f / lrun) : 0.f;
    float* op = aout + ((size_t)b * 2048 + qrow) * 128 + hh * 32 + g * 4;
    *reinterpret_cast<float4*>(op) = make_float4(o0[0] * inv, o0[1] * inv, o0[2] * inv, o0[3] * inv);
    *reinterpret_cast<float4*>(op + 16) = make_float4(o1[0] * inv, o1[1] * inv, o1[2] * inv, o1[3] * inv);
}

// ---------------- LN stats helper (16 rows x 128 cols in LDS) ----------------
__device__ __forceinline__ void ln_stats(const float* buf, float* mu_s, float* rs_s, int tid) {
    int row = tid >> 4, sl = tid & 15;
    float4 x0 = *reinterpret_cast<const float4*>(&buf[row * 128 + sl * 8]);
    float4 x1 = *reinterpret_cast<const float4*>(&buf[row * 128 + sl * 8 + 4]);
    float sum = x0.x + x0.y + x0.z + x0.w + x1.x + x1.y + x1.z + x1.w;
    float sq = x0.x * x0.x + x0.y * x0.y + x0.z * x0.z + x0.w * x0.w +
               x1.x * x1.x + x1.y * x1.y + x1.z * x1.z + x1.w * x1.w;
#pragma unroll
    for (int off = 8; off > 0; off >>= 1) {
        sum += __shfl_xor(sum, off);
        sq += __shfl_xor(sq, off);
    }
    if (sl == 0) {
        float mu = sum * (1.f / 128.f);
        float var = sq * (1.f / 128.f) - mu * mu;
        mu_s[row] = mu;
        rs_s[row] = rsqrtf(var + EPS);
    }
}

// ---------------- fused epilogue: out-proj + res + LN1 + FFN + res + LN2 + mask ----------------
// grid: B*L/16 = 512 blocks, block: 256 threads
__global__ void epilogue_kernel(const float* __restrict__ aout, const float* __restrict__ h,
                                const float* __restrict__ woutT, const float* __restrict__ bout,
                                const float* __restrict__ wff1T, const float* __restrict__ bff1,
                                const float* __restrict__ wff2T, const float* __restrict__ bff2,
                                const float* __restrict__ g1, const float* __restrict__ b1,
                                const float* __restrict__ g2, const float* __restrict__ b2,
                                const float* __restrict__ nmask, float* __restrict__ out) {
    __shared__ __align__(16) float A[16 * 128];
    __shared__ __align__(16) float Hb[16 * 128];
    __shared__ __align__(16) float F[16 * 256];
    __shared__ float mu_s[16], rs_s[16];

    const int tid = threadIdx.x;
    const int row0 = blockIdx.x * 16;
    for (int i = tid; i < 2048; i += 256) {
        A[i] = aout[row0 * 128 + i];
        Hb[i] = h[row0 * 128 + i];
    }
    __syncthreads();

    const int g = tid >> 7, c = tid & 127;

    // --- out-projection ---
    float acc[8];
#pragma unroll
    for (int r = 0; r < 8; ++r) acc[r] = 0.f;
    for (int d0 = 0; d0 < 128; d0 += 4) {
        float w0 = woutT[(d0 + 0) * 128 + c];
        float w1 = woutT[(d0 + 1) * 128 + c];
        float w2 = woutT[(d0 + 2) * 128 + c];
        float w3 = woutT[(d0 + 3) * 128 + c];
#pragma unroll
        for (int r = 0; r < 8; ++r) {
            float4 a4 = *reinterpret_cast<const float4*>(&A[(g * 8 + r) * 128 + d0]);
            acc[r] = fmaf(w0, a4.x, acc[r]);
            acc[r] = fmaf(w1, a4.y, acc[r]);
            acc[r] = fmaf(w2, a4.z, acc[r]);
            acc[r] = fmaf(w3, a4.w, acc[r]);
        }
    }
    float bo = bout[c];
#pragma unroll
    for (int r = 0; r < 8; ++r) {
        int row = g * 8 + r;
        Hb[row * 128 + c] += acc[r] + bo;   // h + attn_out
    }
    __syncthreads();

    ln_stats(Hb, mu_s, rs_s, tid);
    __syncthreads();
    float g1c = g1[c], b1c = b1[c];
#pragma unroll
    for (int r = 0; r < 8; ++r) {
        int row = g * 8 + r;
        float v = (Hb[row * 128 + c] - mu_s[row]) * rs_s[row] * g1c + b1c;
        Hb[row * 128 + c] = v;              // h1
    }
    __syncthreads();

    // --- FF1 + ReLU (thread owns ff column j = tid) ---
    {
        const int j = tid;
        float a2[16];
#pragma unroll
        for (int r = 0; r < 16; ++r) a2[r] = 0.f;
        for (int d0 = 0; d0 < 128; d0 += 4) {
            float w0 = wff1T[(d0 + 0) * 256 + j];
            float w1 = wff1T[(d0 + 1) * 256 + j];
            float w2 = wff1T[(d0 + 2) * 256 + j];
            float w3 = wff1T[(d0 + 3) * 256 + j];
#pragma unroll
            for (int r = 0; r < 16; ++r) {
                float4 h4 = *reinterpret_cast<const float4*>(&Hb[r * 128 + d0]);
                a2[r] = fmaf(w0, h4.x, a2[r]);
                a2[r] = fmaf(w1, h4.y, a2[r]);
                a2[r] = fmaf(w2, h4.z, a2[r]);
                a2[r] = fmaf(w3, h4.w, a2[r]);
            }
        }
        float bj = bff1[j];
#pragma unroll
        for (int r = 0; r < 16; ++r) F[r * 256 + j] = fmaxf(a2[r] + bj, 0.f);
    }
    __syncthreads();

    // --- FF2 + residual ---
    float a3[8];
#pragma unroll
    for (int r = 0; r < 8; ++r) a3[r] = 0.f;
    for (int d0 = 0; d0 < 256; d0 += 4) {
        float w0 = wff2T[(d0 + 0) * 128 + c];
        float w1 = wff2T[(d0 + 1) * 128 + c];
        float w2 = wff2T[(d0 + 2) * 128 + c];
        float w3 = wff2T[(d0 + 3) * 128 + c];
#pragma unroll
        for (int r = 0; r < 8; ++r) {
            float4 f4 = *reinterpret_cast<const float4*>(&F[(g * 8 + r) * 256 + d0]);
            a3[r] = fmaf(w0, f4.x, a3[r]);
            a3[r] = fmaf(w1, f4.y, a3[r]);
            a3[r] = fmaf(w2, f4.z, a3[r]);
            a3[r] = fmaf(w3, f4.w, a3[r]);
        }
    }
    float bo2 = bff2[c];
#pragma unroll
    for (int r = 0; r < 8; ++r) {
        int row = g * 8 + r;
        A[row * 128 + c] = a3[r] + bo2 + Hb[row * 128 + c];   // h1 + ff
    }
    __syncthreads();

    ln_stats(A, mu_s, rs_s, tid);
    __syncthreads();
    float g2c = g2[c], b2c = b2[c];
#pragma unroll
    for (int r = 0; r < 8; ++r) {
        int row = g * 8 + r;
        float nm = nmask[row0 + row];
        float v = (A[row * 128 + c] - mu_s[row]) * rs_s[row] * g2c + b2c;
        out[(row0 + row) * 128 + c] = v * nm;
    }
}

extern "C" void kernel_launch(void* const* d_in, const int* in_sizes, int n_in,
                              void* d_out, int out_size, void* d_ws, size_t ws_size,
                              hipStream_t stream) {
    const float* h = (const float*)d_in[0];
    const float* bias = (const float*)d_in[1];
    const float* nmask = (const float*)d_in[2];
    const void* smask = d_in[3];                 // bool -> byte or int32 (detected)
    const float* w_qkv = (const float*)d_in[4];
    const float* b_qkv = (const float*)d_in[5];
    const float* w_out = (const float*)d_in[6];
    const float* b_out = (const float*)d_in[7];
    const float* w_ff1 = (const float*)d_in[8];
    const float* b_ff1 = (const float*)d_in[9];
    const float* w_ff2 = (const float*)d_in[10];
    const float* b_ff2 = (const float*)d_in[11];
    const float* g1 = (const float*)d_in[12];
    const float* b1 = (const float*)d_in[13];
    const float* g2 = (const float*)d_in[14];
    const float* b2 = (const float*)d_in[15];
    float* out = (float*)d_out;

    char* wsb = (char*)d_ws;
    float* aoutw = (float*)wsb;                               // 4 MB
    unsigned short* qb  = (unsigned short*)(wsb + (4 << 20)); // 2 MB
    unsigned short* kbm = (unsigned short*)(wsb + (6 << 20)); // 2 MB
    unsigned short* vtb = (unsigned short*)(wsb + (8 << 20)); // 2 MB
    unsigned int* cbits = (unsigned int*)(wsb + (10 << 20));  // 2 MB
    float* wqkvT = (float*)(wsb + (12 << 20));                // 192 KB
    float* woutT = wqkvT + 384 * 128;
    float* wff1T = woutT + 128 * 128;
    float* wff2T = wff1T + 256 * 128;

    prep_kernel<<<2560, 256, 0, stream>>>(w_qkv, w_out, w_ff1, w_ff2,
                                          wqkvT, woutT, wff1T, wff2T,
                                          (const unsigned char*)smask, nmask, cbits);
    qkv_kernel<<<512, 384, 0, stream>>>(h, wqkvT, b_qkv, qb, kbm, vtb);
    attn_kernel<<<512, 256, 0, stream>>>(qb, kbm, vtb, bias, cbits, nmask, aoutw);
    epilogue_kernel<<<512, 256, 0, stream>>>(aoutw, h, woutT, b_out, wff1T, b_ff1,
                                             wff2T, b_ff2, g1, b1, g2, b2, nmask, out);
}

// Round 17
// 157.540 us; speedup vs baseline: 1.2142x; 1.0338x over previous
//
#include <hip/hip_runtime.h>
#include <math.h>

#define NEG_INF (-1e9f)
#define EPS 1e-5f

typedef __attribute__((ext_vector_type(8))) short short8;
typedef __attribute__((ext_vector_type(4))) float floatx4;

__device__ __forceinline__ unsigned short f2bf(float x) {
    union { float f; unsigned u; } v; v.f = x;
    unsigned r = v.u + 0x7fffu + ((v.u >> 16) & 1u);
    return (unsigned short)(r >> 16);
}

// async global->LDS, 16B per lane: LDS dest = wave-uniform base + lane*16,
// global src per-lane (enables source pre-swizzle for swizzled LDS layouts).
__device__ __forceinline__ void gl2lds16(const void* g, void* l) {
    __builtin_amdgcn_global_load_lds(
        (const __attribute__((address_space(1))) unsigned int*)g,
        (__attribute__((address_space(3))) unsigned int*)l, 16, 0, 0);
}

// ---------------- weight transposes + mask-storage detect + node-mask pack ----------------
__global__ void transpose_prep_kernel(const float* __restrict__ w_qkv, const float* __restrict__ w_out,
                                      const float* __restrict__ w_ff1, const float* __restrict__ w_ff2,
                                      float* __restrict__ wqkvT, float* __restrict__ woutT,
                                      float* __restrict__ wff1T, float* __restrict__ wff2T,
                                      const unsigned int* __restrict__ sm, int* __restrict__ flag,
                                      const float* __restrict__ nm, unsigned int* __restrict__ nmb) {
    if (blockIdx.x < 512) {
        int idx = blockIdx.x * 256 + threadIdx.x;        // 131072 total
        if (idx < 49152) {
            int r = idx / 128, c = idx % 128;
            wqkvT[c * 384 + r] = w_qkv[idx];
        } else if (idx < 65536) {
            int i = idx - 49152; int r = i / 128, c = i % 128;
            woutT[c * 128 + r] = w_out[i];
        } else if (idx < 98304) {
            int i = idx - 65536; int r = i / 128, c = i % 128;
            wff1T[c * 256 + r] = w_ff1[i];
        } else {
            int i = idx - 98304; int r = i / 256, c = i % 256;
            wff2T[c * 128 + r] = w_ff2[i];
        }
    } else if (blockIdx.x == 512) {
        __shared__ int bad;
        if (threadIdx.x == 0) bad = 0;
        __syncthreads();
        for (int i = threadIdx.x; i < 4096; i += 256) {
            if (sm[i] > 1u) bad = 1;   // impossible for int32 bool storage
        }
        __syncthreads();
        if (threadIdx.x == 0) *flag = bad;   // 1 -> byte storage, 0 -> int32
    } else {
        const int t = threadIdx.x;            // 256 = 4 b * 64 words
        const int b = t >> 6, w32 = t & 63;
        unsigned u = 0;
#pragma unroll
        for (int j = 0; j < 32; ++j)
            u |= (nm[b * 2048 + w32 * 32 + j] > 0.f ? 1u : 0u) << j;
        nmb[t] = u;
    }
}

// ---------------- combined key-mask bits: cbits[(b*2048+q)*64 + k/32] ----------------
__global__ void mask_prep_kernel(const unsigned char* __restrict__ smraw,
                                 const int* __restrict__ flag,
                                 const unsigned int* __restrict__ nmb,
                                 unsigned int* __restrict__ cbits) {
    const int idx = blockIdx.x * 256 + threadIdx.x;   // 524288 total
    const int b = idx >> 17;
    const int q = (idx >> 6) & 2047;
    const int w32 = idx & 63;
    unsigned u = 0;
    if (*flag) {   // byte storage
        const uint4* p = reinterpret_cast<const uint4*>(
            smraw + (size_t)(b * 2048 + q) * 2048 + w32 * 32);
        uint4 a = p[0], c = p[1];
        unsigned wd0 = a.x, wd1 = a.y, wd2 = a.z, wd3 = a.w;
        unsigned wd4 = c.x, wd5 = c.y, wd6 = c.z, wd7 = c.w;
#define BYTES4(v, sh) \
        u |= ((v) & 0xffu ? 1u : 0u) << (sh); \
        u |= ((v) & 0xff00u ? 1u : 0u) << ((sh) + 1); \
        u |= ((v) & 0xff0000u ? 1u : 0u) << ((sh) + 2); \
        u |= ((v) & 0xff000000u ? 1u : 0u) << ((sh) + 3);
        BYTES4(wd0, 0) BYTES4(wd1, 4) BYTES4(wd2, 8) BYTES4(wd3, 12)
        BYTES4(wd4, 16) BYTES4(wd5, 20) BYTES4(wd6, 24) BYTES4(wd7, 28)
#undef BYTES4
    } else {       // int32 storage
        const uint4* p = reinterpret_cast<const uint4*>(
            reinterpret_cast<const unsigned int*>(smraw) + (size_t)(b * 2048 + q) * 2048 + w32 * 32);
#pragma unroll
        for (int wi = 0; wi < 8; ++wi) {
            uint4 a = p[wi];
            u |= (a.x ? 1u : 0u) << (wi * 4);
            u |= (a.y ? 1u : 0u) << (wi * 4 + 1);
            u |= (a.z ? 1u : 0u) << (wi * 4 + 2);
            u |= (a.w ? 1u : 0u) << (wi * 4 + 3);
        }
    }
    cbits[idx] = u & nmb[b * 64 + w32];
}

// ---------------- QKV projection -> bf16 Q,K [bh][l][32]; bf16 V^T [bh][d][k] ----------------
// grid: B*L/16 = 512 blocks, block: 384 threads (one per output column)
__global__ void qkv_kernel(const float* __restrict__ h, const float* __restrict__ wT,
                           const float* __restrict__ bqkv,
                           unsigned short* __restrict__ qb, unsigned short* __restrict__ kbm,
                           unsigned short* __restrict__ vtb) {
    __shared__ __align__(16) float hs[16 * 128];
    const int tid = threadIdx.x;
    const int row0 = blockIdx.x * 16;
    for (int i = tid; i < 2048; i += 384) hs[i] = h[row0 * 128 + i];
    __syncthreads();

    const int c = tid;
    float acc[16];
#pragma unroll
    for (int r = 0; r < 16; ++r) acc[r] = 0.f;

    for (int d0 = 0; d0 < 128; d0 += 4) {
        float w0 = wT[(d0 + 0) * 384 + c];
        float w1 = wT[(d0 + 1) * 384 + c];
        float w2 = wT[(d0 + 2) * 384 + c];
        float w3 = wT[(d0 + 3) * 384 + c];
#pragma unroll
        for (int r = 0; r < 16; ++r) {
            float4 h4 = *reinterpret_cast<const float4*>(&hs[r * 128 + d0]);
            acc[r] = fmaf(w0, h4.x, acc[r]);
            acc[r] = fmaf(w1, h4.y, acc[r]);
            acc[r] = fmaf(w2, h4.z, acc[r]);
            acc[r] = fmaf(w3, h4.w, acc[r]);
        }
    }
    const int part = c >> 7;        // 0=q 1=k 2=v
    const int cc = c & 127;
    const int head = cc >> 5;
    const int dd = cc & 31;
    const float bias = bqkv[c];
    const float scale = (part == 0) ? 0.17677669529663687f : 1.0f; // 1/sqrt(32) into q
#pragma unroll
    for (int r = 0; r < 16; ++r) {
        int grow = row0 + r;
        int b = grow >> 11, l = grow & 2047;
        int bh = b * 4 + head;
        unsigned short val = f2bf((acc[r] + bias) * scale);
        if (part == 0)      qb[((size_t)bh * 2048 + l) * 32 + dd] = val;
        else if (part == 1) kbm[((size_t)bh * 2048 + l) * 32 + dd] = val;
        else                vtb[((size_t)bh * 32 + dd) * 2048 + l] = val;
    }
}

// ---------------- attention: bf16 MFMA, gl2lds staging, counted-vmcnt 2-deep pipeline ------
// grid: 512 blocks (2/CU resident), block: 256 threads = 4 waves, 64 q-rows/block.
// Per 64-k tile the BLOCK stages (async, zero VGPR): K 4KB + V^T 4KB + bias 16KB.
// T3+T4 schedule: raw s_barrier + s_waitcnt vmcnt(6) — next-next tile's 6 loads
// stay in flight across the barrier; never drain to 0 in the main loop.
__global__ __launch_bounds__(256, 2) void attn_kernel(
        const unsigned short* __restrict__ qb, const unsigned short* __restrict__ kbm,
        const unsigned short* __restrict__ vtb, const float* __restrict__ bias,
        const unsigned int* __restrict__ cbits, const float* __restrict__ nmask,
        float* __restrict__ aout) {
    __shared__ __align__(16) unsigned short k_lds[2][64 * 32];   // 2 x 4 KB
    __shared__ __align__(16) unsigned short v_lds[2][32 * 64];   // 2 x 4 KB
    __shared__ __align__(16) float bias_lds[2][64 * 64];         // 2 x 16 KB
    __shared__ __align__(16) unsigned short p_lds[4][16 * 72];   // 9 KB, wave-private

    const int tid = threadIdx.x;
    const int w = tid >> 6, L = tid & 63;
    const int lb = (blockIdx.x & 7) * 64 + (blockIdx.x >> 3);   // bijective, 512%8==0
    const int bh = lb >> 5, qt = lb & 31;
    const int b = bh >> 2, hh = bh & 3;
    const int q0b = qt * 64;                 // block's first q-row
    const int q = L & 15, g = L >> 4;

    const unsigned short* kb_g = kbm + (size_t)bh * 2048 * 32;
    const unsigned short* vb_g = vtb + (size_t)bh * 32 * 2048;
    const float* bias_q0 = bias + ((size_t)bh * 2048 + q0b) * 2048;
    const short8 qf = *reinterpret_cast<const short8*>(
        qb + ((size_t)bh * 2048 + q0b + w * 16 + q) * 32 + g * 8);
    const unsigned int* crow = cbits + (size_t)(b * 2048 + q0b + w * 16 + q) * 64;

    // staging source maps (pre-swizzled so linear LDS == swizzled layout)
    const int r_k = tid >> 2;                                   // K row 0..63
    const size_t k_src0 = (size_t)r_k * 32 + (((tid & 3) ^ (r_k & 3)) << 3);
    const int d_v = tid >> 3;                                   // V^T row 0..31
    const size_t v_src0 = (size_t)d_v * 2048 + (((tid & 7) ^ (d_v & 7)) << 3);
    const int br = tid >> 4;                                    // bias row (mod 16)
    const int bsw = ((tid & 15) ^ br) << 2;                     // swizzled float col

    auto stage = [&](int buf, int kt) {
        const int k0 = kt * 64;
        gl2lds16(kb_g + (size_t)k0 * 32 + k_src0, (char*)(&k_lds[buf][0]) + w * 1024);
        gl2lds16(vb_g + k0 + v_src0, (char*)(&v_lds[buf][0]) + w * 1024);
#pragma unroll
        for (int i = 0; i < 4; ++i)
            gl2lds16(bias_q0 + (size_t)(br + 16 * i) * 2048 + k0 + bsw,
                     (char*)(&bias_lds[buf][0]) + i * 4096 + w * 1024);
    };

    // prologue: 2 tiles in flight, wait for tile 0 only (6 of tile 1 outstanding)
    stage(0, 0);
    stage(1, 1);
    asm volatile("s_waitcnt vmcnt(6)" ::: "memory");
    __builtin_amdgcn_s_barrier();

    float mrun = -3.0e38f, lrun = 0.f;
    floatx4 o0 = {0.f, 0.f, 0.f, 0.f}, o1 = {0.f, 0.f, 0.f, 0.f};
    const floatx4 zacc = {0.f, 0.f, 0.f, 0.f};
    unsigned short* pl = &p_lds[w][q * 72];

    // read-side swizzled offsets (constant per lane)
    const int ksw = (g ^ (q & 3)) << 4;       // K col16 swizzle
    const int vsw0 = ((g) ^ (q & 7)) << 4;    // V col16 (k 0..31)
    const int vsw1 = ((g + 4) ^ (q & 7)) << 4;// V col16 (k 32..63)
    const int brow = (w * 16 + q) * 256;      // bias row byte offset

    for (int t = 0; t < 32; ++t) {
        const int cur = t & 1;

        // ---- fragments from LDS ----
        const char* kl = (const char*)(&k_lds[cur][0]);
        short8 kf0 = *reinterpret_cast<const short8*>(kl + (q     ) * 64 + ksw);
        short8 kf1 = *reinterpret_cast<const short8*>(kl + (16 + q) * 64 + ksw);
        short8 kf2 = *reinterpret_cast<const short8*>(kl + (32 + q) * 64 + ksw);
        short8 kf3 = *reinterpret_cast<const short8*>(kl + (48 + q) * 64 + ksw);
        const char* vl = (const char*)(&v_lds[cur][0]);
        short8 vf00 = *reinterpret_cast<const short8*>(vl + (q     ) * 128 + vsw0);
        short8 vf01 = *reinterpret_cast<const short8*>(vl + (q     ) * 128 + vsw1);
        short8 vf10 = *reinterpret_cast<const short8*>(vl + (16 + q) * 128 + vsw0);
        short8 vf11 = *reinterpret_cast<const short8*>(vl + (16 + q) * 128 + vsw1);
        uint2 cw = *reinterpret_cast<const uint2*>(crow + t * 2);

        // ---- QK^T ----
        float s[16];
        {
            floatx4 r0 = __builtin_amdgcn_mfma_f32_16x16x32_bf16(kf0, qf, zacc, 0, 0, 0);
            floatx4 r1 = __builtin_amdgcn_mfma_f32_16x16x32_bf16(kf1, qf, zacc, 0, 0, 0);
            floatx4 r2 = __builtin_amdgcn_mfma_f32_16x16x32_bf16(kf2, qf, zacc, 0, 0, 0);
            floatx4 r3 = __builtin_amdgcn_mfma_f32_16x16x32_bf16(kf3, qf, zacc, 0, 0, 0);
            s[0] = r0[0]; s[1] = r0[1]; s[2] = r0[2]; s[3] = r0[3];
            s[4] = r1[0]; s[5] = r1[1]; s[6] = r1[2]; s[7] = r1[3];
            s[8] = r2[0]; s[9] = r2[1]; s[10] = r2[2]; s[11] = r2[3];
            s[12] = r3[0]; s[13] = r3[1]; s[14] = r3[2]; s[15] = r3[3];
        }
        // ---- bias fragments from LDS (swizzled rows -> 2-way, free) ----
        const char* bl = (const char*)(&bias_lds[cur][0]);
        float4 bq0 = *reinterpret_cast<const float4*>(bl + brow + (((0 + g) ^ q) << 4));
        float4 bq1 = *reinterpret_cast<const float4*>(bl + brow + (((4 + g) ^ q) << 4));
        float4 bq2 = *reinterpret_cast<const float4*>(bl + brow + (((8 + g) ^ q) << 4));
        float4 bq3 = *reinterpret_cast<const float4*>(bl + brow + (((12 + g) ^ q) << 4));
        float bvv[16];
        bvv[0] = bq0.x; bvv[1] = bq0.y; bvv[2] = bq0.z; bvv[3] = bq0.w;
        bvv[4] = bq1.x; bvv[5] = bq1.y; bvv[6] = bq1.z; bvv[7] = bq1.w;
        bvv[8] = bq2.x; bvv[9] = bq2.y; bvv[10] = bq2.z; bvv[11] = bq2.w;
        bvv[12] = bq3.x; bvv[13] = bq3.y; bvv[14] = bq3.z; bvv[15] = bq3.w;
#pragma unroll
        for (int i = 0; i < 16; ++i) {
            const int mm = i >> 2, reg = i & 3;
            const unsigned word = (mm < 2) ? cw.x : cw.y;
            const int sh = 16 * (mm & 1) + 4 * g + reg;
            const bool keep = (word >> sh) & 1;
            s[i] = keep ? (s[i] + bvv[i]) : NEG_INF;
        }
        // ---- online softmax (in-lane 16 + 2 shfl) ----
        float tm = s[0];
#pragma unroll
        for (int i = 1; i < 16; ++i) tm = fmaxf(tm, s[i]);
        tm = fmaxf(tm, __shfl_xor(tm, 16));
        tm = fmaxf(tm, __shfl_xor(tm, 32));
        const float mn = fmaxf(mrun, tm);
        const float f = __expf(mrun - mn);
        mrun = mn;
        float p[16], ts = 0.f;
#pragma unroll
        for (int i = 0; i < 16; ++i) { p[i] = __expf(s[i] - mn); ts += p[i]; }
        ts += __shfl_xor(ts, 16);
        ts += __shfl_xor(ts, 32);
        lrun = lrun * f + ts;
        o0 *= f; o1 *= f;
        // ---- pack P -> bf16, stage in wave-private LDS row (stride 72) ----
#pragma unroll
        for (int mm = 0; mm < 4; ++mm) {
            unsigned u0 = (unsigned)f2bf(p[4 * mm]) | ((unsigned)f2bf(p[4 * mm + 1]) << 16);
            unsigned u1 = (unsigned)f2bf(p[4 * mm + 2]) | ((unsigned)f2bf(p[4 * mm + 3]) << 16);
            *reinterpret_cast<unsigned int*>(pl + 16 * mm + 4 * g) = u0;
            *reinterpret_cast<unsigned int*>(pl + 16 * mm + 4 * g + 2) = u1;
        }
        // ---- PV: B-frag = own row's 8 consecutive k ----
        short8 pb0 = *reinterpret_cast<const short8*>(pl + g * 8);
        short8 pb1 = *reinterpret_cast<const short8*>(pl + 32 + g * 8);
        o0 = __builtin_amdgcn_mfma_f32_16x16x32_bf16(vf00, pb0, o0, 0, 0, 0);
        o0 = __builtin_amdgcn_mfma_f32_16x16x32_bf16(vf01, pb1, o0, 0, 0, 0);
        o1 = __builtin_amdgcn_mfma_f32_16x16x32_bf16(vf10, pb0, o1, 0, 0, 0);
        o1 = __builtin_amdgcn_mfma_f32_16x16x32_bf16(vf11, pb1, o1, 0, 0, 0);

        // ---- pipeline advance: free buf[cur], restage it with tile t+2 ----
        if (t < 31) {
            __builtin_amdgcn_s_barrier();          // all waves done reading buf[cur]
            if (t + 2 < 32) {
                stage(cur, t + 2);                 // 6 async loads into freed buffer
                asm volatile("s_waitcnt vmcnt(6)" ::: "memory");  // t+1's loads retired
            } else {
                asm volatile("s_waitcnt vmcnt(0)" ::: "memory");  // tail: drain last tile
            }
            __builtin_amdgcn_s_barrier();          // everyone's t+1 data visible
        }
    }

    // ---- epilogue: normalize, query mask, write ----
    const int qrow = q0b + w * 16 + q;
    const float nmq = nmask[b * 2048 + qrow];
    const float inv = (nmq > 0.f) ? (1.f / lrun) : 0.f;
    float* op = aout + ((size_t)b * 2048 + qrow) * 128 + hh * 32 + g * 4;
    *reinterpret_cast<float4*>(op) = make_float4(o0[0] * inv, o0[1] * inv, o0[2] * inv, o0[3] * inv);
    *reinterpret_cast<float4*>(op + 16) = make_float4(o1[0] * inv, o1[1] * inv, o1[2] * inv, o1[3] * inv);
}

// ---------------- LN stats helper (16 rows x 128 cols in LDS) ----------------
__device__ __forceinline__ void ln_stats(const float* buf, float* mu_s, float* rs_s, int tid) {
    int row = tid >> 4, sl = tid & 15;
    float4 x0 = *reinterpret_cast<const float4*>(&buf[row * 128 + sl * 8]);
    float4 x1 = *reinterpret_cast<const float4*>(&buf[row * 128 + sl * 8 + 4]);
    float sum = x0.x + x0.y + x0.z + x0.w + x1.x + x1.y + x1.z + x1.w;
    float sq = x0.x * x0.x + x0.y * x0.y + x0.z * x0.z + x0.w * x0.w +
               x1.x * x1.x + x1.y * x1.y + x1.z * x1.z + x1.w * x1.w;
#pragma unroll
    for (int off = 8; off > 0; off >>= 1) {
        sum += __shfl_xor(sum, off);
        sq += __shfl_xor(sq, off);
    }
    if (sl == 0) {
        float mu = sum * (1.f / 128.f);
        float var = sq * (1.f / 128.f) - mu * mu;
        mu_s[row] = mu;
        rs_s[row] = rsqrtf(var + EPS);
    }
}

// ---------------- fused epilogue: out-proj + res + LN1 + FFN + res + LN2 + mask ----------------
// grid: B*L/16 = 512 blocks, block: 256 threads
__global__ void epilogue_kernel(const float* __restrict__ aout, const float* __restrict__ h,
                                const float* __restrict__ woutT, const float* __restrict__ bout,
                                const float* __restrict__ wff1T, const float* __restrict__ bff1,
                                const float* __restrict__ wff2T, const float* __restrict__ bff2,
                                const float* __restrict__ g1, const float* __restrict__ b1,
                                const float* __restrict__ g2, const float* __restrict__ b2,
                                const float* __restrict__ nmask, float* __restrict__ out) {
    __shared__ __align__(16) float A[16 * 128];
    __shared__ __align__(16) float Hb[16 * 128];
    __shared__ __align__(16) float F[16 * 256];
    __shared__ float mu_s[16], rs_s[16];

    const int tid = threadIdx.x;
    const int row0 = blockIdx.x * 16;
    for (int i = tid; i < 2048; i += 256) {
        A[i] = aout[row0 * 128 + i];
        Hb[i] = h[row0 * 128 + i];
    }
    __syncthreads();

    const int g = tid >> 7, c = tid & 127;

    // --- out-projection ---
    float acc[8];
#pragma unroll
    for (int r = 0; r < 8; ++r) acc[r] = 0.f;
    for (int d0 = 0; d0 < 128; d0 += 4) {
        float w0 = woutT[(d0 + 0) * 128 + c];
        float w1 = woutT[(d0 + 1) * 128 + c];
        float w2 = woutT[(d0 + 2) * 128 + c];
        float w3 = woutT[(d0 + 3) * 128 + c];
#pragma unroll
        for (int r = 0; r < 8; ++r) {
            float4 a4 = *reinterpret_cast<const float4*>(&A[(g * 8 + r) * 128 + d0]);
            acc[r] = fmaf(w0, a4.x, acc[r]);
            acc[r] = fmaf(w1, a4.y, acc[r]);
            acc[r] = fmaf(w2, a4.z, acc[r]);
            acc[r] = fmaf(w3, a4.w, acc[r]);
        }
    }
    float bo = bout[c];
#pragma unroll
    for (int r = 0; r < 8; ++r) {
        int row = g * 8 + r;
        Hb[row * 128 + c] += acc[r] + bo;   // h + attn_out
    }
    __syncthreads();

    ln_stats(Hb, mu_s, rs_s, tid);
    __syncthreads();
    float g1c = g1[c], b1c = b1[c];
#pragma unroll
    for (int r = 0; r < 8; ++r) {
        int row = g * 8 + r;
        float v = (Hb[row * 128 + c] - mu_s[row]) * rs_s[row] * g1c + b1c;
        Hb[row * 128 + c] = v;              // h1
    }
    __syncthreads();

    // --- FF1 + ReLU (thread owns ff column j = tid) ---
    {
        const int j = tid;
        float a2[16];
#pragma unroll
        for (int r = 0; r < 16; ++r) a2[r] = 0.f;
        for (int d0 = 0; d0 < 128; d0 += 4) {
            float w0 = wff1T[(d0 + 0) * 256 + j];
            float w1 = wff1T[(d0 + 1) * 256 + j];
            float w2 = wff1T[(d0 + 2) * 256 + j];
            float w3 = wff1T[(d0 + 3) * 256 + j];
#pragma unroll
            for (int r = 0; r < 16; ++r) {
                float4 h4 = *reinterpret_cast<const float4*>(&Hb[r * 128 + d0]);
                a2[r] = fmaf(w0, h4.x, a2[r]);
                a2[r] = fmaf(w1, h4.y, a2[r]);
                a2[r] = fmaf(w2, h4.z, a2[r]);
                a2[r] = fmaf(w3, h4.w, a2[r]);
            }
        }
        float bj = bff1[j];
#pragma unroll
        for (int r = 0; r < 16; ++r) F[r * 256 + j] = fmaxf(a2[r] + bj, 0.f);
    }
    __syncthreads();

    // --- FF2 + residual ---
    float a3[8];
#pragma unroll
    for (int r = 0; r < 8; ++r) a3[r] = 0.f;
    for (int d0 = 0; d0 < 256; d0 += 4) {
        float w0 = wff2T[(d0 + 0) * 128 + c];
        float w1 = wff2T[(d0 + 1) * 128 + c];
        float w2 = wff2T[(d0 + 2) * 128 + c];
        float w3 = wff2T[(d0 + 3) * 128 + c];
#pragma unroll
        for (int r = 0; r < 8; ++r) {
            float4 f4 = *reinterpret_cast<const float4*>(&F[(g * 8 + r) * 256 + d0]);
            a3[r] = fmaf(w0, f4.x, a3[r]);
            a3[r] = fmaf(w1, f4.y, a3[r]);
            a3[r] = fmaf(w2, f4.z, a3[r]);
            a3[r] = fmaf(w3, f4.w, a3[r]);
        }
    }
    float bo2 = bff2[c];
#pragma unroll
    for (int r = 0; r < 8; ++r) {
        int row = g * 8 + r;
        A[row * 128 + c] = a3[r] + bo2 + Hb[row * 128 + c];   // h1 + ff
    }
    __syncthreads();

    ln_stats(A, mu_s, rs_s, tid);
    __syncthreads();
    float g2c = g2[c], b2c = b2[c];
#pragma unroll
    for (int r = 0; r < 8; ++r) {
        int row = g * 8 + r;
        float nm = nmask[row0 + row];
        float v = (A[row * 128 + c] - mu_s[row]) * rs_s[row] * g2c + b2c;
        out[(row0 + row) * 128 + c] = v * nm;
    }
}

extern "C" void kernel_launch(void* const* d_in, const int* in_sizes, int n_in,
                              void* d_out, int out_size, void* d_ws, size_t ws_size,
                              hipStream_t stream) {
    const float* h = (const float*)d_in[0];
    const float* bias = (const float*)d_in[1];
    const float* nmask = (const float*)d_in[2];
    const void* smask = d_in[3];                 // bool -> byte or int32 (detected)
    const float* w_qkv = (const float*)d_in[4];
    const float* b_qkv = (const float*)d_in[5];
    const float* w_out = (const float*)d_in[6];
    const float* b_out = (const float*)d_in[7];
    const float* w_ff1 = (const float*)d_in[8];
    const float* b_ff1 = (const float*)d_in[9];
    const float* w_ff2 = (const float*)d_in[10];
    const float* b_ff2 = (const float*)d_in[11];
    const float* g1 = (const float*)d_in[12];
    const float* b1 = (const float*)d_in[13];
    const float* g2 = (const float*)d_in[14];
    const float* b2 = (const float*)d_in[15];
    float* out = (float*)d_out;

    char* wsb = (char*)d_ws;
    float* aoutw = (float*)wsb;                               // 4 MB
    unsigned short* qb  = (unsigned short*)(wsb + (4 << 20)); // 2 MB
    unsigned short* kbm = (unsigned short*)(wsb + (6 << 20)); // 2 MB
    unsigned short* vtb = (unsigned short*)(wsb + (8 << 20)); // 2 MB
    unsigned int* cbits = (unsigned int*)(wsb + (10 << 20));  // 2 MB
    unsigned int* nmb   = (unsigned int*)(wsb + (12 << 20));  // 1 KB
    float* wqkvT = (float*)(wsb + (12 << 20) + 4096);         // 192 KB
    float* woutT = wqkvT + 384 * 128;
    float* wff1T = woutT + 128 * 128;
    float* wff2T = wff1T + 256 * 128;
    int* smflag = (int*)(wff2T + 128 * 256);

    transpose_prep_kernel<<<514, 256, 0, stream>>>(w_qkv, w_out, w_ff1, w_ff2,
                                                   wqkvT, woutT, wff1T, wff2T,
                                                   (const unsigned int*)smask, smflag,
                                                   nmask, nmb);
    mask_prep_kernel<<<2048, 256, 0, stream>>>((const unsigned char*)smask, smflag, nmb, cbits);
    qkv_kernel<<<512, 384, 0, stream>>>(h, wqkvT, b_qkv, qb, kbm, vtb);
    attn_kernel<<<512, 256, 0, stream>>>(qb, kbm, vtb, bias, cbits, nmask, aoutw);
    epilogue_kernel<<<512, 256, 0, stream>>>(aoutw, h, woutT, b_out, wff1T, b_ff1,
                                             wff2T, b_ff2, g1, b1, g2, b2, nmask, out);
}